// Round 1
// baseline (410.462 us; speedup 1.0000x reference)
//
#include <hip/hip_runtime.h>
#include <math.h>

// Problem constants
constexpr int kB   = 16;
constexpr int kNL  = 4096;
constexpr int kNH  = 1024;
constexpr int kCL  = 128;
constexpr int kCH  = 256;
constexpr int kINC = 384;   // kCH + kCL
constexpr int kOUT = 256;

// ---------------------------------------------------------------------------
// Kernel 1: transpose feat_high (B, CH, NH) -> FHT (B, NH, CH)
// so that gathering "all channels of high-point j" is a coalesced 1 KB read.
// ---------------------------------------------------------------------------
__global__ void k_transpose_fh(const float* __restrict__ fh, float* __restrict__ fht) {
    __shared__ float tile[64][65];
    int b  = blockIdx.z;
    int j0 = blockIdx.x * 64;   // NH tile
    int c0 = blockIdx.y * 64;   // CH tile
    const float* src = fh  + (size_t)b * kCH * kNH;
    float*       dst = fht + (size_t)b * kNH * kCH;
    #pragma unroll
    for (int i = 0; i < 16; ++i) {
        int e = threadIdx.x + i * 256;
        int c = e >> 6, j = e & 63;
        tile[c][j] = src[(c0 + c) * kNH + j0 + j];
    }
    __syncthreads();
    #pragma unroll
    for (int i = 0; i < 16; ++i) {
        int e = threadIdx.x + i * 256;
        int j = e >> 6, c = e & 63;
        dst[(j0 + j) * kCH + c0 + c] = tile[c][j];
    }
}

// ---------------------------------------------------------------------------
// Kernel 2: three_nn. One thread per low point; xyz_high staged in LDS.
// Distance formula matches the reference EXACTLY (expanded form, no fma
// contraction) so near-tie top-3 ordering agrees with the np reference.
// ---------------------------------------------------------------------------
__global__ void k_three_nn(const float* __restrict__ xyzl, const float* __restrict__ xyzh,
                           float* __restrict__ w3, int* __restrict__ idx3) {
    __shared__ float xh[kNH], yh[kNH], zh[kNH], sh[kNH];
    int b = blockIdx.y;
    int t = threadIdx.x;
    const float* H = xyzh + (size_t)b * kNH * 3;
    for (int e = t; e < kNH * 3; e += 256) {
        int j = e / 3, d = e % 3;
        float v = H[e];
        if (d == 0) xh[j] = v; else if (d == 1) yh[j] = v; else zh[j] = v;
    }
    __syncthreads();
    for (int j = t; j < kNH; j += 256) {
        // (x*x + y*y) + z*z, round-to-nearest each step (matches np sum order)
        float a = __fmul_rn(xh[j], xh[j]);
        a = __fadd_rn(a, __fmul_rn(yh[j], yh[j]));
        a = __fadd_rn(a, __fmul_rn(zh[j], zh[j]));
        sh[j] = a;
    }
    __syncthreads();

    int l = blockIdx.x * 256 + t;
    const float* L = xyzl + ((size_t)b * kNL + l) * 3;
    float x = L[0], y = L[1], z = L[2];
    float sql = __fmul_rn(x, x);
    sql = __fadd_rn(sql, __fmul_rn(y, y));
    sql = __fadd_rn(sql, __fmul_rn(z, z));

    float d0 = 1e30f, d1 = 1e30f, d2 = 1e30f;
    int   i0 = 0,     i1 = 0,     i2 = 0;
    for (int j = 0; j < kNH; ++j) {
        float inner = __fmul_rn(x, xh[j]);
        inner = __fadd_rn(inner, __fmul_rn(y, yh[j]));
        inner = __fadd_rn(inner, __fmul_rn(z, zh[j]));
        // (sql + sqh) - 2*inner, clipped at 0 — exactly the reference's order
        float dsq = __fsub_rn(__fadd_rn(sql, sh[j]), __fmul_rn(2.0f, inner));
        dsq = fmaxf(dsq, 0.0f);
        if (dsq < d2) {
            if (dsq < d0)      { d2 = d1; i2 = i1; d1 = d0; i1 = i0; d0 = dsq; i0 = j; }
            else if (dsq < d1) { d2 = d1; i2 = i1; d1 = dsq; i1 = j; }
            else               { d2 = dsq; i2 = j; }
        }
    }
    float e0 = fmaxf(sqrtf(d0), 1e-8f);
    float e1 = fmaxf(sqrtf(d1), 1e-8f);
    float e2 = fmaxf(sqrtf(d2), 1e-8f);
    float r0 = 1.0f / e0, r1 = 1.0f / e1, r2 = 1.0f / e2;
    float s  = __fadd_rn(__fadd_rn(r0, r1), r2);
    int base = ((size_t)b * kNL + l) * 3;
    w3[base + 0] = r0 / s;  w3[base + 1] = r1 / s;  w3[base + 2] = r2 / s;
    idx3[base + 0] = i0;    idx3[base + 1] = i1;    idx3[base + 2] = i2;
}

// ---------------------------------------------------------------------------
// Kernel 3: fused interpolate + concat + (W @ f_cat + bias) GEMM.
// Block = (batch b, 64-column tile). LDS: F[384][65] (f_cat tile, pad keeps
// all accesses <=2-way bank aliased = free), Ws[32][260] (W k-chunk,
// transposed + 16B-aligned rows for float4 reads).
// Thread micro-tile: 16 channels x 4 columns.
// ---------------------------------------------------------------------------
__global__ __launch_bounds__(256, 1)
void k_gemm(const float* __restrict__ fht, const float* __restrict__ flow,
            const float* __restrict__ W, const float* __restrict__ bias,
            const float* __restrict__ w3, const int* __restrict__ idx3,
            float* __restrict__ out) {
    __shared__ float F[kINC][65];
    __shared__ float Ws[32][260];
    __shared__ float wc[64][3];
    __shared__ int   ic[64][3];

    int b  = blockIdx.y;
    int n0 = blockIdx.x * 64;
    int t  = threadIdx.x;

    if (t < 192) {
        int n = t / 3, k = t % 3;
        wc[n][k] = w3[((size_t)b * kNL + n0 + n) * 3 + k];
        ic[n][k] = idx3[((size_t)b * kNL + n0 + n) * 3 + k];
    }
    __syncthreads();

    // --- interp rows 0..255: thread owns channel c = t, loops 64 columns ---
    {
        const float* FHT = fht + (size_t)b * kNH * kCH;
        int c = t;
        #pragma unroll 4
        for (int n = 0; n < 64; ++n) {
            float a = wc[n][0] * FHT[ic[n][0] * kCH + c];
            a = fmaf(wc[n][1], FHT[ic[n][1] * kCH + c], a);
            a = fmaf(wc[n][2], FHT[ic[n][2] * kCH + c], a);
            F[c][n] = a;
        }
    }
    // --- feat_low rows 256..383 ---
    {
        const float* FL = flow + (size_t)b * kCL * kNL;
        #pragma unroll
        for (int i = 0; i < 8; ++i) {
            int e4 = t + i * 256;            // float4 index into 128x16 tile
            int c = e4 >> 4, n4 = e4 & 15;
            float4 v = *(const float4*)&FL[c * kNL + n0 + n4 * 4];
            F[kCH + c][n4 * 4 + 0] = v.x;
            F[kCH + c][n4 * 4 + 1] = v.y;
            F[kCH + c][n4 * 4 + 2] = v.z;
            F[kCH + c][n4 * 4 + 3] = v.w;
        }
    }
    __syncthreads();

    int tx = t & 15;   // column group: cols tx*4 .. tx*4+3
    int ty = t >> 4;   // channel group: ch ty*16 .. ty*16+15
    float acc[16][4];
    #pragma unroll
    for (int i = 0; i < 16; ++i)
        #pragma unroll
        for (int j = 0; j < 4; ++j) acc[i][j] = 0.0f;

    for (int kc = 0; kc < kINC; kc += 32) {
        // stage W chunk transposed: Ws[kk][o]
        #pragma unroll
        for (int i = 0; i < 32; ++i) {
            int e = t + i * 256;
            int o = e >> 5, kk = e & 31;
            Ws[kk][o] = W[o * kINC + kc + kk];
        }
        __syncthreads();
        #pragma unroll 8
        for (int kk = 0; kk < 32; ++kk) {
            float f0 = F[kc + kk][tx * 4 + 0];
            float f1 = F[kc + kk][tx * 4 + 1];
            float f2 = F[kc + kk][tx * 4 + 2];
            float f3 = F[kc + kk][tx * 4 + 3];
            const float4* wp = (const float4*)&Ws[kk][ty * 16];
            float4 wa = wp[0], wb = wp[1], wcc = wp[2], wd = wp[3];
            float wreg[16] = {wa.x, wa.y, wa.z, wa.w, wb.x, wb.y, wb.z, wb.w,
                              wcc.x, wcc.y, wcc.z, wcc.w, wd.x, wd.y, wd.z, wd.w};
            #pragma unroll
            for (int i = 0; i < 16; ++i) {
                acc[i][0] = fmaf(wreg[i], f0, acc[i][0]);
                acc[i][1] = fmaf(wreg[i], f1, acc[i][1]);
                acc[i][2] = fmaf(wreg[i], f2, acc[i][2]);
                acc[i][3] = fmaf(wreg[i], f3, acc[i][3]);
            }
        }
        __syncthreads();
    }

    // epilogue: + bias, store y tile into d_out
    float* Y = out + (size_t)b * kOUT * kNL + n0;
    #pragma unroll
    for (int i = 0; i < 16; ++i) {
        int o = ty * 16 + i;
        float bb = bias[o];
        float4 v;
        v.x = acc[i][0] + bb; v.y = acc[i][1] + bb;
        v.z = acc[i][2] + bb; v.w = acc[i][3] + bb;
        *(float4*)&Y[o * kNL + tx * 4] = v;
    }
}

// ---------------------------------------------------------------------------
// Kernel 4: per-(channel, batch) partial sum / sumsq over the 4096 columns.
// Deterministic (no atomics).
// ---------------------------------------------------------------------------
__global__ void k_stats(const float* __restrict__ y, float* __restrict__ ps,
                        float* __restrict__ pq) {
    int o = blockIdx.x, b = blockIdx.y, t = threadIdx.x;
    const float4* row = (const float4*)(y + ((size_t)(b * kOUT + o)) * kNL);
    float s = 0.0f, q = 0.0f;
    #pragma unroll
    for (int i = 0; i < 4; ++i) {
        float4 v = row[t + i * 256];
        s += v.x + v.y + v.z + v.w;
        q += v.x * v.x + v.y * v.y + v.z * v.z + v.w * v.w;
    }
    #pragma unroll
    for (int off = 32; off > 0; off >>= 1) {
        s += __shfl_down(s, off);
        q += __shfl_down(q, off);
    }
    __shared__ float ls[4], lq[4];
    if ((t & 63) == 0) { ls[t >> 6] = s; lq[t >> 6] = q; }
    __syncthreads();
    if (t == 0) {
        s = ls[0] + ls[1] + ls[2] + ls[3];
        q = lq[0] + lq[1] + lq[2] + lq[3];
        ps[o * kB + b] = s;
        pq[o * kB + b] = q;
    }
}

// ---------------------------------------------------------------------------
// Kernel 5: finalize BN coeffs: a = gamma*rstd, c = beta - mean*a
// ---------------------------------------------------------------------------
__global__ void k_finalize(const float* __restrict__ ps, const float* __restrict__ pq,
                           const float* __restrict__ gamma, const float* __restrict__ beta,
                           float* __restrict__ cA, float* __restrict__ cB) {
    int o = threadIdx.x;
    float s = 0.0f, q = 0.0f;
    #pragma unroll
    for (int b = 0; b < kB; ++b) { s += ps[o * kB + b]; q += pq[o * kB + b]; }
    const float inv = 1.0f / (float)(kB * kNL);
    float mean = s * inv;
    float var  = q * inv - mean * mean;
    float a = gamma[o] * rsqrtf(var + 1e-5f);
    cA[o] = a;
    cB[o] = beta[o] - mean * a;
}

// ---------------------------------------------------------------------------
// Kernel 6: in-place normalize + ReLU on d_out, float4-vectorized.
// ---------------------------------------------------------------------------
__global__ void k_apply(float* __restrict__ y, const float* __restrict__ cA,
                        const float* __restrict__ cB) {
    size_t idx    = (size_t)blockIdx.x * 256 + threadIdx.x;
    size_t stride = (size_t)gridDim.x * 256;
    const size_t n4 = (size_t)kB * kOUT * kNL / 4;
    float4* p = (float4*)y;
    for (size_t i = idx; i < n4; i += stride) {
        int o = (int)((i >> 10) & 255);   // 1024 float4 per (b,o) row
        float a = cA[o], c = cB[o];
        float4 v = p[i];
        v.x = fmaxf(fmaf(a, v.x, c), 0.0f);
        v.y = fmaxf(fmaf(a, v.y, c), 0.0f);
        v.z = fmaxf(fmaf(a, v.z, c), 0.0f);
        v.w = fmaxf(fmaf(a, v.w, c), 0.0f);
        p[i] = v;
    }
}

// ---------------------------------------------------------------------------
extern "C" void kernel_launch(void* const* d_in, const int* in_sizes, int n_in,
                              void* d_out, int out_size, void* d_ws, size_t ws_size,
                              hipStream_t stream) {
    const float* xyzl  = (const float*)d_in[0];
    const float* xyzh  = (const float*)d_in[1];
    const float* flow  = (const float*)d_in[2];
    const float* fhigh = (const float*)d_in[3];
    const float* W     = (const float*)d_in[4];
    const float* bias  = (const float*)d_in[5];
    const float* gamma = (const float*)d_in[6];
    const float* beta  = (const float*)d_in[7];
    float* out = (float*)d_out;
    float* ws  = (float*)d_ws;

    // ws layout (floats)
    float* w3   = ws;                        // 16*4096*3      = 196608
    int*   idx3 = (int*)(ws + 196608);       //                = 196608
    float* fht  = ws + 393216;               // 16*1024*256    = 4194304
    float* ps   = ws + 4587520;              // 256*16         = 4096
    float* pq   = ws + 4591616;              // 256*16         = 4096
    float* cA   = ws + 4595712;              // 256
    float* cB   = ws + 4595968;              // 256
    (void)ws_size; (void)in_sizes; (void)n_in; (void)out_size;

    hipLaunchKernelGGL(k_transpose_fh, dim3(kNH / 64, kCH / 64, kB), dim3(256), 0, stream,
                       fhigh, fht);
    hipLaunchKernelGGL(k_three_nn, dim3(kNL / 256, kB), dim3(256), 0, stream,
                       xyzl, xyzh, w3, idx3);
    hipLaunchKernelGGL(k_gemm, dim3(kNL / 64, kB), dim3(256), 0, stream,
                       fht, flow, W, bias, w3, idx3, out);
    hipLaunchKernelGGL(k_stats, dim3(kOUT, kB), dim3(256), 0, stream, out, ps, pq);
    hipLaunchKernelGGL(k_finalize, dim3(1), dim3(256), 0, stream, ps, pq, gamma, beta, cA, cB);
    hipLaunchKernelGGL(k_apply, dim3(2048), dim3(256), 0, stream, out, cA, cB);
}

// Round 2
// 170.951 us; speedup vs baseline: 2.4011x; 2.4011x over previous
//
#include <hip/hip_runtime.h>
#include <math.h>

constexpr int kB   = 16;
constexpr int kNL  = 4096;
constexpr int kNH  = 1024;
constexpr int kCL  = 128;
constexpr int kCH  = 256;
constexpr int kOUT = 256;

typedef __attribute__((ext_vector_type(8))) short s16x8;
typedef __attribute__((ext_vector_type(4))) float f32x4;

__device__ __forceinline__ unsigned short f2bf(float x) {
    unsigned int u = __float_as_uint(x);
    return (unsigned short)((u + 0x7FFFu + ((u >> 16) & 1u)) >> 16);
}

// ---------------------------------------------------------------------------
// W (256x384 f32) -> W1bf (256x256 bf16, cols 0..255), W2bf (256x128 bf16)
// ---------------------------------------------------------------------------
__global__ void k_prep_w(const float* __restrict__ W, unsigned short* __restrict__ w1,
                         unsigned short* __restrict__ w2) {
    int o = blockIdx.x, k = threadIdx.x;
    float v = W[o * 384 + k];
    if (k < kCH) w1[o * kCH + k] = f2bf(v);
    else         w2[o * kCL + (k - kCH)] = f2bf(v);
}

// feat_high (B,CH,NH) f32 -> FHT_bf (B,NH,CH) bf16
__global__ void k_prep_fht(const float* __restrict__ fh, unsigned short* __restrict__ fht) {
    __shared__ float tile[64][65];
    int b = blockIdx.z, j0 = blockIdx.x * 64, c0 = blockIdx.y * 64;
    const float* src = fh + (size_t)b * kCH * kNH;
    unsigned short* dst = fht + (size_t)b * kNH * kCH;
    #pragma unroll
    for (int i = 0; i < 16; ++i) {
        int e = threadIdx.x + i * 256, c = e >> 6, j = e & 63;
        tile[c][j] = src[(size_t)(c0 + c) * kNH + j0 + j];
    }
    __syncthreads();
    #pragma unroll
    for (int i = 0; i < 16; ++i) {
        int e = threadIdx.x + i * 256, j = e >> 6, c = e & 63;
        dst[(size_t)(j0 + j) * kCH + c0 + c] = f2bf(tile[c][j]);
    }
}

// feat_low (B,CL,NL) f32 -> FLT_bf (B,NL,CL) bf16
__global__ void k_prep_flt(const float* __restrict__ fl, unsigned short* __restrict__ flt) {
    __shared__ float tile[64][65];
    int b = blockIdx.z, n0 = blockIdx.x * 64, c0 = blockIdx.y * 64;
    const float* src = fl + (size_t)b * kCL * kNL;
    unsigned short* dst = flt + (size_t)b * kNL * kCL;
    #pragma unroll
    for (int i = 0; i < 16; ++i) {
        int e = threadIdx.x + i * 256, c = e >> 6, n = e & 63;
        tile[c][n] = src[(size_t)(c0 + c) * kNL + n0 + n];
    }
    __syncthreads();
    #pragma unroll
    for (int i = 0; i < 16; ++i) {
        int e = threadIdx.x + i * 256, n = e >> 6, c = e & 63;
        dst[(size_t)(n0 + n) * kCL + c0 + c] = f2bf(tile[c][n]);
    }
}

// ---------------------------------------------------------------------------
// three_nn: 4 threads per low point (j-range split 4x256), exact fp32
// distances (reference's non-fused expansion), (d, idx)-lexicographic merge
// matching jax.lax.top_k tie-breaking (lower index wins on equal distance).
// ---------------------------------------------------------------------------
__global__ __launch_bounds__(256) void k_three_nn(
    const float* __restrict__ xyzl, const float* __restrict__ xyzh,
    float* __restrict__ w3, int* __restrict__ idx3)
{
    __shared__ float xh[kNH], yh[kNH], zh[kNH], sh[kNH];
    __shared__ float md[64][4][3];
    __shared__ int   midx[64][4][3];
    int b = blockIdx.y, t = threadIdx.x;
    const float* H = xyzh + (size_t)b * kNH * 3;
    for (int e = t; e < kNH * 3; e += 256) {
        int j = e / 3, d = e - j * 3;
        float v = H[e];
        if (d == 0) xh[j] = v; else if (d == 1) yh[j] = v; else zh[j] = v;
    }
    __syncthreads();
    for (int j = t; j < kNH; j += 256) {
        float a = __fmul_rn(xh[j], xh[j]);
        a = __fadd_rn(a, __fmul_rn(yh[j], yh[j]));
        a = __fadd_rn(a, __fmul_rn(zh[j], zh[j]));
        sh[j] = a;
    }
    __syncthreads();

    int sub = t >> 6, ll = t & 63;
    int l = blockIdx.x * 64 + ll;
    const float* L = xyzl + ((size_t)b * kNL + l) * 3;
    float x = L[0], y = L[1], z = L[2];
    float sql = __fmul_rn(x, x);
    sql = __fadd_rn(sql, __fmul_rn(y, y));
    sql = __fadd_rn(sql, __fmul_rn(z, z));

    float d0 = 1e30f, d1 = 1e30f, d2 = 1e30f;
    int   i0 = 0,     i1 = 0,     i2 = 0;
    int jbeg = sub * 256;
    for (int j = jbeg; j < jbeg + 256; ++j) {
        float inner = __fmul_rn(x, xh[j]);
        inner = __fadd_rn(inner, __fmul_rn(y, yh[j]));
        inner = __fadd_rn(inner, __fmul_rn(z, zh[j]));
        float dsq = __fsub_rn(__fadd_rn(sql, sh[j]), __fmul_rn(2.0f, inner));
        dsq = fmaxf(dsq, 0.0f);
        if (dsq < d2) {
            if (dsq < d0)      { d2 = d1; i2 = i1; d1 = d0; i1 = i0; d0 = dsq; i0 = j; }
            else if (dsq < d1) { d2 = d1; i2 = i1; d1 = dsq; i1 = j; }
            else               { d2 = dsq; i2 = j; }
        }
    }
    md[ll][sub][0] = d0; md[ll][sub][1] = d1; md[ll][sub][2] = d2;
    midx[ll][sub][0] = i0; midx[ll][sub][1] = i1; midx[ll][sub][2] = i2;
    __syncthreads();

    if (sub == 0) {
        float e0 = 1e30f, e1 = 1e30f, e2 = 1e30f;
        int   a0 = 0x7fffffff, a1 = 0x7fffffff, a2 = 0x7fffffff;
        #pragma unroll
        for (int s = 0; s < 4; ++s) {
            #pragma unroll
            for (int k = 0; k < 3; ++k) {
                float d = md[ll][s][k]; int ii = midx[ll][s][k];
                bool lt2 = (d < e2) || (d == e2 && ii < a2);
                if (lt2) {
                    bool lt0 = (d < e0) || (d == e0 && ii < a0);
                    bool lt1 = (d < e1) || (d == e1 && ii < a1);
                    if (lt0)      { e2 = e1; a2 = a1; e1 = e0; a1 = a0; e0 = d; a0 = ii; }
                    else if (lt1) { e2 = e1; a2 = a1; e1 = d; a1 = ii; }
                    else          { e2 = d; a2 = ii; }
                }
            }
        }
        float q0 = fmaxf(sqrtf(e0), 1e-8f);
        float q1 = fmaxf(sqrtf(e1), 1e-8f);
        float q2 = fmaxf(sqrtf(e2), 1e-8f);
        float r0 = 1.0f / q0, r1 = 1.0f / q1, r2 = 1.0f / q2;
        float s = __fadd_rn(__fadd_rn(r0, r1), r2);
        size_t base = ((size_t)b * kNL + l) * 3;
        w3[base + 0] = r0 / s;  w3[base + 1] = r1 / s;  w3[base + 2] = r2 / s;
        idx3[base + 0] = a0;    idx3[base + 1] = a1;    idx3[base + 2] = a2;
    }
}

// ---------------------------------------------------------------------------
// GEMM1 (MFMA bf16): G = W1 (256x256) x feat_high (256x1024) per batch.
// Stored transposed GT[b][j][o] (f32) so the gemm2 gather reads contiguous o.
// Block: 256 out x 64 j, 4 waves (wave = 64 out x 64 j, 4x4 16x16 frags).
// ---------------------------------------------------------------------------
__global__ __launch_bounds__(256, 4) void k_gemm1(
    const unsigned short* __restrict__ fht, const unsigned short* __restrict__ w1,
    float* __restrict__ gt)
{
    __shared__ __align__(16) unsigned short Bt[64][264];  // stride 528B = 132dw ≡ 4 mod 32
    int b = blockIdx.y, j0 = blockIdx.x * 64, t = threadIdx.x;
    const unsigned short* src = fht + ((size_t)b * kNH + j0) * kCH;
    #pragma unroll
    for (int i = 0; i < 8; ++i) {
        int e = t + i * 256, j = e >> 5, u = e & 31;
        *(s16x8*)(&Bt[j][u * 8]) = *(const s16x8*)(src + (size_t)j * kCH + u * 8);
    }
    __syncthreads();

    int w = t >> 6, lane = t & 63, lo = lane & 15, hi = lane >> 4;
    f32x4 vz = {0.f, 0.f, 0.f, 0.f};
    f32x4 acc[4][4];
    #pragma unroll
    for (int mi = 0; mi < 4; ++mi)
        #pragma unroll
        for (int ni = 0; ni < 4; ++ni) acc[mi][ni] = vz;

    #pragma unroll
    for (int ks = 0; ks < 8; ++ks) {
        s16x8 av[4], bv[4];
        #pragma unroll
        for (int mi = 0; mi < 4; ++mi)
            av[mi] = *(const s16x8*)(w1 + (size_t)(64 * w + 16 * mi + lo) * kCH + ks * 32 + hi * 8);
        #pragma unroll
        for (int ni = 0; ni < 4; ++ni)
            bv[ni] = *(const s16x8*)(&Bt[16 * ni + lo][ks * 32 + hi * 8]);
        #pragma unroll
        for (int mi = 0; mi < 4; ++mi)
            #pragma unroll
            for (int ni = 0; ni < 4; ++ni)
                acc[mi][ni] = __builtin_amdgcn_mfma_f32_16x16x32_bf16(av[mi], bv[ni], acc[mi][ni], 0, 0, 0);
    }

    float* G = gt + ((size_t)b * kNH + j0) * kOUT;
    #pragma unroll
    for (int mi = 0; mi < 4; ++mi)
        #pragma unroll
        for (int ni = 0; ni < 4; ++ni)
            *(f32x4*)(&G[(size_t)(16 * ni + lo) * kOUT + 64 * w + 16 * mi + 4 * hi]) = acc[mi][ni];
}

// ---------------------------------------------------------------------------
// GEMM2 (MFMA bf16) + fused interp-gather + bias + partial BN stats.
// y = W2 (256x128) x feat_low + sum_k w_k * GT[idx_k] + bias.
// Block: 256 out x 64 cols of one batch. Stats reduced via LDS table (union
// with the B tile) -> ps/pq[o][block], no y re-read for stats.
// ---------------------------------------------------------------------------
__global__ __launch_bounds__(256, 3) void k_gemm2(
    const unsigned short* __restrict__ flt, const unsigned short* __restrict__ w2,
    const float* __restrict__ gt, const float* __restrict__ bias,
    const float* __restrict__ w3, const int* __restrict__ idx3,
    float* __restrict__ y, float* __restrict__ ps, float* __restrict__ pq)
{
    __shared__ __align__(16) char smem[36864];           // union: Bt | red
    unsigned short (*Bt)[136] = (unsigned short (*)[136])smem;  // 272B = 68dw ≡ 4 mod 32
    f32x4 (*red)[9] = (f32x4 (*)[9])smem;                // 144B rows, 2-way on writes
    __shared__ float wc[64][3];
    __shared__ int   ic[64][3];

    int b = blockIdx.y, n0 = blockIdx.x * 64, t = threadIdx.x;
    int blin = b * gridDim.x + blockIdx.x;               // 0..1023

    if (t < 192) {
        int n = t / 3, k = t - n * 3;
        wc[n][k] = w3[((size_t)b * kNL + n0 + n) * 3 + k];
        ic[n][k] = idx3[((size_t)b * kNL + n0 + n) * 3 + k];
    }
    const unsigned short* src = flt + ((size_t)b * kNL + n0) * kCL;
    #pragma unroll
    for (int i = 0; i < 4; ++i) {
        int e = t + i * 256, n = e >> 4, u = e & 15;
        *(s16x8*)(&Bt[n][u * 8]) = *(const s16x8*)(src + (size_t)n * kCL + u * 8);
    }
    __syncthreads();

    int w = t >> 6, lane = t & 63, lo = lane & 15, hi = lane >> 4;
    f32x4 vz = {0.f, 0.f, 0.f, 0.f};
    f32x4 acc[4][4];
    #pragma unroll
    for (int mi = 0; mi < 4; ++mi)
        #pragma unroll
        for (int ni = 0; ni < 4; ++ni) acc[mi][ni] = vz;

    #pragma unroll
    for (int ks = 0; ks < 4; ++ks) {
        s16x8 av[4], bv[4];
        #pragma unroll
        for (int mi = 0; mi < 4; ++mi)
            av[mi] = *(const s16x8*)(w2 + (size_t)(64 * w + 16 * mi + lo) * kCL + ks * 32 + hi * 8);
        #pragma unroll
        for (int ni = 0; ni < 4; ++ni)
            bv[ni] = *(const s16x8*)(&Bt[16 * ni + lo][ks * 32 + hi * 8]);
        #pragma unroll
        for (int mi = 0; mi < 4; ++mi)
            #pragma unroll
            for (int ni = 0; ni < 4; ++ni)
                acc[mi][ni] = __builtin_amdgcn_mfma_f32_16x16x32_bf16(av[mi], bv[ni], acc[mi][ni], 0, 0, 0);
    }

    // epilogue: interp gather from GT (L2-resident, 1 MB/batch) + bias
    const float* G = gt + (size_t)b * kNH * kOUT;
    #pragma unroll
    for (int ni = 0; ni < 4; ++ni) {
        int lc = 16 * ni + lo;
        #pragma unroll
        for (int k = 0; k < 3; ++k) {
            int   jj = ic[lc][k];
            float wg = wc[lc][k];
            const float* Gj = G + (size_t)jj * kOUT + 64 * w + 4 * hi;
            #pragma unroll
            for (int mi = 0; mi < 4; ++mi) {
                f32x4 g = *(const f32x4*)(Gj + 16 * mi);
                acc[mi][ni] += g * wg;
            }
        }
    }
    #pragma unroll
    for (int mi = 0; mi < 4; ++mi) {
        f32x4 bb = *(const f32x4*)(bias + 64 * w + 16 * mi + 4 * hi);
        #pragma unroll
        for (int ni = 0; ni < 4; ++ni) acc[mi][ni] += bb;
    }

    // store y (f32) into d_out
    float* Y = y + (size_t)b * kOUT * kNL + n0;
    #pragma unroll
    for (int mi = 0; mi < 4; ++mi)
        #pragma unroll
        for (int ni = 0; ni < 4; ++ni)
            #pragma unroll
            for (int r = 0; r < 4; ++r)
                Y[(size_t)(64 * w + 16 * mi + 4 * hi + r) * kNL + 16 * ni + lo] = acc[mi][ni][r];

    // fused partial BN stats: per-o sums over this block's 64 columns
    __syncthreads();   // done with Bt; smem becomes red
    #pragma unroll
    for (int mi = 0; mi < 4; ++mi) {
        f32x4 s = acc[mi][0] + acc[mi][1] + acc[mi][2] + acc[mi][3];
        f32x4 q = acc[mi][0] * acc[mi][0] + acc[mi][1] * acc[mi][1]
                + acc[mi][2] * acc[mi][2] + acc[mi][3] * acc[mi][3];
        red[t][mi] = s;
        red[t][4 + mi] = q;
    }
    __syncthreads();
    {
        int o = t;
        int ow = o >> 6, omi = (o >> 4) & 3, ohi = (o >> 2) & 3, orr = o & 3;
        float s = 0.0f, q = 0.0f;
        #pragma unroll
        for (int l2 = 0; l2 < 16; ++l2) {
            int srct = ow * 64 + ohi * 16 + l2;
            s += red[srct][omi][orr];
            q += red[srct][4 + omi][orr];
        }
        ps[(size_t)o * 1024 + blin] = s;
        pq[(size_t)o * 1024 + blin] = q;
    }
}

// ---------------------------------------------------------------------------
// finalize: reduce 1024 partials per channel -> affine coeffs
// ---------------------------------------------------------------------------
__global__ void k_finalize(const float* __restrict__ ps, const float* __restrict__ pq,
                           const float* __restrict__ gamma, const float* __restrict__ beta,
                           float* __restrict__ cA, float* __restrict__ cB) {
    int o = blockIdx.x, t = threadIdx.x;
    float s = 0.0f, q = 0.0f;
    #pragma unroll
    for (int i = 0; i < 4; ++i) {
        s += ps[(size_t)o * 1024 + t + i * 256];
        q += pq[(size_t)o * 1024 + t + i * 256];
    }
    #pragma unroll
    for (int off = 32; off > 0; off >>= 1) {
        s += __shfl_down(s, off);
        q += __shfl_down(q, off);
    }
    __shared__ float ls[4], lq[4];
    if ((t & 63) == 0) { ls[t >> 6] = s; lq[t >> 6] = q; }
    __syncthreads();
    if (t == 0) {
        s = ls[0] + ls[1] + ls[2] + ls[3];
        q = lq[0] + lq[1] + lq[2] + lq[3];
        const float inv = 1.0f / (float)(kB * kNL);
        float mean = s * inv;
        float var  = q * inv - mean * mean;
        float a = gamma[o] * rsqrtf(var + 1e-5f);
        cA[o] = a;
        cB[o] = beta[o] - mean * a;
    }
}

// ---------------------------------------------------------------------------
// apply: in-place normalize + ReLU on d_out, float4
// ---------------------------------------------------------------------------
__global__ void k_apply(float* __restrict__ y, const float* __restrict__ cA,
                        const float* __restrict__ cB) {
    size_t idx    = (size_t)blockIdx.x * 256 + threadIdx.x;
    size_t stride = (size_t)gridDim.x * 256;
    const size_t n4 = (size_t)kB * kOUT * kNL / 4;
    float4* p = (float4*)y;
    for (size_t i = idx; i < n4; i += stride) {
        int o = (int)((i >> 10) & 255);
        float a = cA[o], c = cB[o];
        float4 v = p[i];
        v.x = fmaxf(fmaf(a, v.x, c), 0.0f);
        v.y = fmaxf(fmaf(a, v.y, c), 0.0f);
        v.z = fmaxf(fmaf(a, v.z, c), 0.0f);
        v.w = fmaxf(fmaf(a, v.w, c), 0.0f);
        p[i] = v;
    }
}

// ---------------------------------------------------------------------------
extern "C" void kernel_launch(void* const* d_in, const int* in_sizes, int n_in,
                              void* d_out, int out_size, void* d_ws, size_t ws_size,
                              hipStream_t stream) {
    const float* xyzl  = (const float*)d_in[0];
    const float* xyzh  = (const float*)d_in[1];
    const float* flow  = (const float*)d_in[2];
    const float* fhigh = (const float*)d_in[3];
    const float* W     = (const float*)d_in[4];
    const float* bias  = (const float*)d_in[5];
    const float* gamma = (const float*)d_in[6];
    const float* beta  = (const float*)d_in[7];
    float* out = (float*)d_out;
    char*  ws  = (char*)d_ws;
    (void)in_sizes; (void)n_in; (void)out_size; (void)ws_size;

    // ws layout (bytes); FLT overlays FHT (FHT dead after gemm1)
    float*          w3    = (float*)(ws + 0);                  //  0.79 MB
    int*            idx3  = (int*)  (ws + 786432);             //  0.79 MB
    float*          gt    = (float*)(ws + 1572864);            // 16 MB
    unsigned short* fht   = (unsigned short*)(ws + 18350080);  // 8 MB (shared region, 16 MB)
    unsigned short* flt   = (unsigned short*)(ws + 18350080);  // 16 MB (overlay after gemm1)
    unsigned short* w1    = (unsigned short*)(ws + 35127296);  // 128 KB
    unsigned short* w2    = (unsigned short*)(ws + 35258368);  // 64 KB
    float*          ps    = (float*)(ws + 35323904);           // 1 MB
    float*          pq    = (float*)(ws + 36372480);           // 1 MB
    float*          cA    = (float*)(ws + 37421056);
    float*          cB    = (float*)(ws + 37422080);

    hipLaunchKernelGGL(k_prep_w,   dim3(256),            dim3(384), 0, stream, W, w1, w2);
    hipLaunchKernelGGL(k_prep_fht, dim3(16, 4, kB),      dim3(256), 0, stream, fhigh, fht);
    hipLaunchKernelGGL(k_three_nn, dim3(kNL / 64, kB),   dim3(256), 0, stream, xyzl, xyzh, w3, idx3);
    hipLaunchKernelGGL(k_gemm1,    dim3(kNH / 64, kB),   dim3(256), 0, stream, fht, w1, gt);
    hipLaunchKernelGGL(k_prep_flt, dim3(kNL / 64, 2, kB),dim3(256), 0, stream, flow, flt);
    hipLaunchKernelGGL(k_gemm2,    dim3(kNL / 64, kB),   dim3(256), 0, stream,
                       flt, w2, gt, bias, w3, idx3, out, ps, pq);
    hipLaunchKernelGGL(k_finalize, dim3(256),            dim3(256), 0, stream, ps, pq, gamma, beta, cA, cB);
    hipLaunchKernelGGL(k_apply,    dim3(2048),           dim3(256), 0, stream, out, cA, cB);
}

// Round 3
// 156.173 us; speedup vs baseline: 2.6283x; 1.0946x over previous
//
#include <hip/hip_runtime.h>
#include <math.h>

constexpr int kB   = 16;
constexpr int kNL  = 4096;
constexpr int kNH  = 1024;
constexpr int kCL  = 128;
constexpr int kCH  = 256;
constexpr int kOUT = 256;

typedef __attribute__((ext_vector_type(8))) short s16x8;
typedef __attribute__((ext_vector_type(4))) float f32x4;

__device__ __forceinline__ unsigned short f2bf(float x) {
    unsigned int u = __float_as_uint(x);
    return (unsigned short)((u + 0x7FFFu + ((u >> 16) & 1u)) >> 16);
}

// ---------------------------------------------------------------------------
// W (256x384 f32) -> W1bf (256x256 bf16, cols 0..255), W2bf (256x128 bf16)
// ---------------------------------------------------------------------------
__global__ void k_prep_w(const float* __restrict__ W, unsigned short* __restrict__ w1,
                         unsigned short* __restrict__ w2) {
    int o = blockIdx.x, k = threadIdx.x;
    float v = W[o * 384 + k];
    if (k < kCH) w1[o * kCH + k] = f2bf(v);
    else         w2[o * kCL + (k - kCH)] = f2bf(v);
}

// feat_high (B,CH,NH) f32 -> FHT_bf (B,NH,CH) bf16
__global__ void k_prep_fht(const float* __restrict__ fh, unsigned short* __restrict__ fht) {
    __shared__ float tile[64][65];
    int b = blockIdx.z, j0 = blockIdx.x * 64, c0 = blockIdx.y * 64;
    const float* src = fh + (size_t)b * kCH * kNH;
    unsigned short* dst = fht + (size_t)b * kNH * kCH;
    #pragma unroll
    for (int i = 0; i < 16; ++i) {
        int e = threadIdx.x + i * 256, c = e >> 6, j = e & 63;
        tile[c][j] = src[(size_t)(c0 + c) * kNH + j0 + j];
    }
    __syncthreads();
    #pragma unroll
    for (int i = 0; i < 16; ++i) {
        int e = threadIdx.x + i * 256, j = e >> 6, c = e & 63;
        dst[(size_t)(j0 + j) * kCH + c0 + c] = f2bf(tile[c][j]);
    }
}

// feat_low (B,CL,NL) f32 -> FLT_bf (B,NL,CL) bf16
__global__ void k_prep_flt(const float* __restrict__ fl, unsigned short* __restrict__ flt) {
    __shared__ float tile[64][65];
    int b = blockIdx.z, n0 = blockIdx.x * 64, c0 = blockIdx.y * 64;
    const float* src = fl + (size_t)b * kCL * kNL;
    unsigned short* dst = flt + (size_t)b * kNL * kCL;
    #pragma unroll
    for (int i = 0; i < 16; ++i) {
        int e = threadIdx.x + i * 256, c = e >> 6, n = e & 63;
        tile[c][n] = src[(size_t)(c0 + c) * kNL + n0 + n];
    }
    __syncthreads();
    #pragma unroll
    for (int i = 0; i < 16; ++i) {
        int e = threadIdx.x + i * 256, n = e >> 6, c = e & 63;
        dst[(size_t)(n0 + n) * kCL + c0 + c] = f2bf(tile[c][n]);
    }
}

// ---------------------------------------------------------------------------
// Candidate table for three_nn: cand[b][j] = {2x, 2y, 2z, x^2+y^2+z^2}.
// Pre-doubling is exact (scaling by 2 commutes with fp rounding), so the
// distance below is bit-identical to the reference's (sql+sqh) - 2*inner.
// ---------------------------------------------------------------------------
__global__ void k_prep_cand(const float* __restrict__ xyzh, float4* __restrict__ cand) {
    int b = blockIdx.x;
    const float* H = xyzh + (size_t)b * kNH * 3;
    for (int j = threadIdx.x; j < kNH; j += 256) {
        float xx = H[j * 3 + 0], yy = H[j * 3 + 1], zz = H[j * 3 + 2];
        float s = __fmul_rn(xx, xx);
        s = __fadd_rn(s, __fmul_rn(yy, yy));
        s = __fadd_rn(s, __fmul_rn(zz, zz));
        cand[(size_t)b * kNH + j] = make_float4(xx + xx, yy + yy, zz + zz, s);
    }
}

// ---------------------------------------------------------------------------
// three_nn v3: candidates fetched via wave-uniform SCALAR loads (s_load_dwordx4
// from the cand table; base forced uniform with readfirstlane), branchless
// 3-deep insert (3 v_cmp + 10 v_cndmask). 4 threads per point (j-split),
// lexicographic (d, idx) merge = jax.lax.top_k tie semantics.
// ---------------------------------------------------------------------------
__global__ __launch_bounds__(256) void k_three_nn(
    const float* __restrict__ xyzl, const float4* __restrict__ cand,
    float* __restrict__ w3, int* __restrict__ idx3)
{
    __shared__ float md[64][4][3];
    __shared__ int   midx[64][4][3];
    int b = blockIdx.y, t = threadIdx.x;
    int sub = t >> 6, ll = t & 63;
    int l = blockIdx.x * 64 + ll;

    const float* L = xyzl + ((size_t)b * kNL + l) * 3;
    float x = L[0], y = L[1], z = L[2];
    float sql = __fmul_rn(x, x);
    sql = __fadd_rn(sql, __fmul_rn(y, y));
    sql = __fadd_rn(sql, __fmul_rn(z, z));

    float d0 = 1e30f, d1 = 1e30f, d2 = 1e30f;
    int   i0 = 0,     i1 = 0,     i2 = 0;

    int jbeg = __builtin_amdgcn_readfirstlane(sub << 8);
    const float4* C = cand + ((size_t)b << 10) + jbeg;
    #pragma unroll 8
    for (int jj = 0; jj < 256; ++jj) {
        float4 c = C[jj];                       // uniform addr -> s_load_dwordx4
        float inner2 = __fmul_rn(x, c.x);       // == 2*inner, bit-exact
        inner2 = __fadd_rn(inner2, __fmul_rn(y, c.y));
        inner2 = __fadd_rn(inner2, __fmul_rn(z, c.z));
        float dsq = __fsub_rn(__fadd_rn(sql, c.w), inner2);
        dsq = fmaxf(dsq, 0.0f);
        int j = jbeg + jj;
        bool c0 = dsq < d0, c1 = dsq < d1, c2 = dsq < d2;
        float td = c1 ? d1 : dsq;  int ti = c1 ? i1 : j;
        d2 = c2 ? td : d2;         i2 = c2 ? ti : i2;
        td = c0 ? d0 : dsq;        ti = c0 ? i0 : j;
        d1 = c1 ? td : d1;         i1 = c1 ? ti : i1;
        d0 = c0 ? dsq : d0;        i0 = c0 ? j : i0;
    }

    md[ll][sub][0] = d0;  md[ll][sub][1] = d1;  md[ll][sub][2] = d2;
    midx[ll][sub][0] = i0; midx[ll][sub][1] = i1; midx[ll][sub][2] = i2;
    __syncthreads();

    if (sub == 0) {
        float e0 = 1e30f, e1 = 1e30f, e2 = 1e30f;
        int   a0 = 0x7fffffff, a1 = 0x7fffffff, a2 = 0x7fffffff;
        #pragma unroll
        for (int s = 0; s < 4; ++s) {
            #pragma unroll
            for (int k = 0; k < 3; ++k) {
                float d = md[ll][s][k]; int ii = midx[ll][s][k];
                bool lt2 = (d < e2) || (d == e2 && ii < a2);
                if (lt2) {
                    bool lt0 = (d < e0) || (d == e0 && ii < a0);
                    bool lt1 = (d < e1) || (d == e1 && ii < a1);
                    if (lt0)      { e2 = e1; a2 = a1; e1 = e0; a1 = a0; e0 = d; a0 = ii; }
                    else if (lt1) { e2 = e1; a2 = a1; e1 = d; a1 = ii; }
                    else          { e2 = d; a2 = ii; }
                }
            }
        }
        float q0 = fmaxf(sqrtf(e0), 1e-8f);
        float q1 = fmaxf(sqrtf(e1), 1e-8f);
        float q2 = fmaxf(sqrtf(e2), 1e-8f);
        float r0 = 1.0f / q0, r1 = 1.0f / q1, r2 = 1.0f / q2;
        float s = __fadd_rn(__fadd_rn(r0, r1), r2);
        size_t base = ((size_t)b * kNL + l) * 3;
        w3[base + 0] = r0 / s;  w3[base + 1] = r1 / s;  w3[base + 2] = r2 / s;
        idx3[base + 0] = a0;    idx3[base + 1] = a1;    idx3[base + 2] = a2;
    }
}

// ---------------------------------------------------------------------------
// GEMM1 (MFMA bf16): G = W1 (256x256) x feat_high (256x1024) per batch.
// Stored transposed GT[b][j][o] (f32) so the gemm2 gather reads contiguous o.
// ---------------------------------------------------------------------------
__global__ __launch_bounds__(256, 4) void k_gemm1(
    const unsigned short* __restrict__ fht, const unsigned short* __restrict__ w1,
    float* __restrict__ gt)
{
    __shared__ __align__(16) unsigned short Bt[64][264];
    int b = blockIdx.y, j0 = blockIdx.x * 64, t = threadIdx.x;
    const unsigned short* src = fht + ((size_t)b * kNH + j0) * kCH;
    #pragma unroll
    for (int i = 0; i < 8; ++i) {
        int e = t + i * 256, j = e >> 5, u = e & 31;
        *(s16x8*)(&Bt[j][u * 8]) = *(const s16x8*)(src + (size_t)j * kCH + u * 8);
    }
    __syncthreads();

    int w = t >> 6, lane = t & 63, lo = lane & 15, hi = lane >> 4;
    f32x4 vz = {0.f, 0.f, 0.f, 0.f};
    f32x4 acc[4][4];
    #pragma unroll
    for (int mi = 0; mi < 4; ++mi)
        #pragma unroll
        for (int ni = 0; ni < 4; ++ni) acc[mi][ni] = vz;

    #pragma unroll
    for (int ks = 0; ks < 8; ++ks) {
        s16x8 av[4], bv[4];
        #pragma unroll
        for (int mi = 0; mi < 4; ++mi)
            av[mi] = *(const s16x8*)(w1 + (size_t)(64 * w + 16 * mi + lo) * kCH + ks * 32 + hi * 8);
        #pragma unroll
        for (int ni = 0; ni < 4; ++ni)
            bv[ni] = *(const s16x8*)(&Bt[16 * ni + lo][ks * 32 + hi * 8]);
        #pragma unroll
        for (int mi = 0; mi < 4; ++mi)
            #pragma unroll
            for (int ni = 0; ni < 4; ++ni)
                acc[mi][ni] = __builtin_amdgcn_mfma_f32_16x16x32_bf16(av[mi], bv[ni], acc[mi][ni], 0, 0, 0);
    }

    float* G = gt + ((size_t)b * kNH + j0) * kOUT;
    #pragma unroll
    for (int mi = 0; mi < 4; ++mi)
        #pragma unroll
        for (int ni = 0; ni < 4; ++ni)
            *(f32x4*)(&G[(size_t)(16 * ni + lo) * kOUT + 64 * w + 16 * mi + 4 * hi]) = acc[mi][ni];
}

// ---------------------------------------------------------------------------
// GEMM2 (MFMA bf16) + fused interp-gather + bias + partial BN stats.
// ---------------------------------------------------------------------------
__global__ __launch_bounds__(256, 3) void k_gemm2(
    const unsigned short* __restrict__ flt, const unsigned short* __restrict__ w2,
    const float* __restrict__ gt, const float* __restrict__ bias,
    const float* __restrict__ w3, const int* __restrict__ idx3,
    float* __restrict__ y, float* __restrict__ ps, float* __restrict__ pq)
{
    __shared__ __align__(16) char smem[36864];           // union: Bt | red
    unsigned short (*Bt)[136] = (unsigned short (*)[136])smem;
    f32x4 (*red)[9] = (f32x4 (*)[9])smem;
    __shared__ float wc[64][3];
    __shared__ int   ic[64][3];

    int b = blockIdx.y, n0 = blockIdx.x * 64, t = threadIdx.x;
    int blin = b * gridDim.x + blockIdx.x;

    if (t < 192) {
        int n = t / 3, k = t - n * 3;
        wc[n][k] = w3[((size_t)b * kNL + n0 + n) * 3 + k];
        ic[n][k] = idx3[((size_t)b * kNL + n0 + n) * 3 + k];
    }
    const unsigned short* src = flt + ((size_t)b * kNL + n0) * kCL;
    #pragma unroll
    for (int i = 0; i < 4; ++i) {
        int e = t + i * 256, n = e >> 4, u = e & 15;
        *(s16x8*)(&Bt[n][u * 8]) = *(const s16x8*)(src + (size_t)n * kCL + u * 8);
    }
    __syncthreads();

    int w = t >> 6, lane = t & 63, lo = lane & 15, hi = lane >> 4;
    f32x4 vz = {0.f, 0.f, 0.f, 0.f};
    f32x4 acc[4][4];
    #pragma unroll
    for (int mi = 0; mi < 4; ++mi)
        #pragma unroll
        for (int ni = 0; ni < 4; ++ni) acc[mi][ni] = vz;

    #pragma unroll
    for (int ks = 0; ks < 4; ++ks) {
        s16x8 av[4], bv[4];
        #pragma unroll
        for (int mi = 0; mi < 4; ++mi)
            av[mi] = *(const s16x8*)(w2 + (size_t)(64 * w + 16 * mi + lo) * kCL + ks * 32 + hi * 8);
        #pragma unroll
        for (int ni = 0; ni < 4; ++ni)
            bv[ni] = *(const s16x8*)(&Bt[16 * ni + lo][ks * 32 + hi * 8]);
        #pragma unroll
        for (int mi = 0; mi < 4; ++mi)
            #pragma unroll
            for (int ni = 0; ni < 4; ++ni)
                acc[mi][ni] = __builtin_amdgcn_mfma_f32_16x16x32_bf16(av[mi], bv[ni], acc[mi][ni], 0, 0, 0);
    }

    // epilogue: interp gather from GT (L2-resident, 1 MB/batch) + bias
    const float* G = gt + (size_t)b * kNH * kOUT;
    #pragma unroll
    for (int ni = 0; ni < 4; ++ni) {
        int lc = 16 * ni + lo;
        #pragma unroll
        for (int k = 0; k < 3; ++k) {
            int   jj = ic[lc][k];
            float wg = wc[lc][k];
            const float* Gj = G + (size_t)jj * kOUT + 64 * w + 4 * hi;
            #pragma unroll
            for (int mi = 0; mi < 4; ++mi) {
                f32x4 g = *(const f32x4*)(Gj + 16 * mi);
                acc[mi][ni] += g * wg;
            }
        }
    }
    #pragma unroll
    for (int mi = 0; mi < 4; ++mi) {
        f32x4 bb = *(const f32x4*)(bias + 64 * w + 16 * mi + 4 * hi);
        #pragma unroll
        for (int ni = 0; ni < 4; ++ni) acc[mi][ni] += bb;
    }

    float* Y = y + (size_t)b * kOUT * kNL + n0;
    #pragma unroll
    for (int mi = 0; mi < 4; ++mi)
        #pragma unroll
        for (int ni = 0; ni < 4; ++ni)
            #pragma unroll
            for (int r = 0; r < 4; ++r)
                Y[(size_t)(64 * w + 16 * mi + 4 * hi + r) * kNL + 16 * ni + lo] = acc[mi][ni][r];

    __syncthreads();
    #pragma unroll
    for (int mi = 0; mi < 4; ++mi) {
        f32x4 s = acc[mi][0] + acc[mi][1] + acc[mi][2] + acc[mi][3];
        f32x4 q = acc[mi][0] * acc[mi][0] + acc[mi][1] * acc[mi][1]
                + acc[mi][2] * acc[mi][2] + acc[mi][3] * acc[mi][3];
        red[t][mi] = s;
        red[t][4 + mi] = q;
    }
    __syncthreads();
    {
        int o = t;
        int ow = o >> 6, omi = (o >> 4) & 3, ohi = (o >> 2) & 3, orr = o & 3;
        float s = 0.0f, q = 0.0f;
        #pragma unroll
        for (int l2 = 0; l2 < 16; ++l2) {
            int srct = ow * 64 + ohi * 16 + l2;
            s += red[srct][omi][orr];
            q += red[srct][4 + omi][orr];
        }
        ps[(size_t)o * 1024 + blin] = s;
        pq[(size_t)o * 1024 + blin] = q;
    }
}

// ---------------------------------------------------------------------------
__global__ void k_finalize(const float* __restrict__ ps, const float* __restrict__ pq,
                           const float* __restrict__ gamma, const float* __restrict__ beta,
                           float* __restrict__ cA, float* __restrict__ cB) {
    int o = blockIdx.x, t = threadIdx.x;
    float s = 0.0f, q = 0.0f;
    #pragma unroll
    for (int i = 0; i < 4; ++i) {
        s += ps[(size_t)o * 1024 + t + i * 256];
        q += pq[(size_t)o * 1024 + t + i * 256];
    }
    #pragma unroll
    for (int off = 32; off > 0; off >>= 1) {
        s += __shfl_down(s, off);
        q += __shfl_down(q, off);
    }
    __shared__ float ls[4], lq[4];
    if ((t & 63) == 0) { ls[t >> 6] = s; lq[t >> 6] = q; }
    __syncthreads();
    if (t == 0) {
        s = ls[0] + ls[1] + ls[2] + ls[3];
        q = lq[0] + lq[1] + lq[2] + lq[3];
        const float inv = 1.0f / (float)(kB * kNL);
        float mean = s * inv;
        float var  = q * inv - mean * mean;
        float a = gamma[o] * rsqrtf(var + 1e-5f);
        cA[o] = a;
        cB[o] = beta[o] - mean * a;
    }
}

// ---------------------------------------------------------------------------
__global__ void k_apply(float* __restrict__ y, const float* __restrict__ cA,
                        const float* __restrict__ cB) {
    size_t idx    = (size_t)blockIdx.x * 256 + threadIdx.x;
    size_t stride = (size_t)gridDim.x * 256;
    const size_t n4 = (size_t)kB * kOUT * kNL / 4;
    float4* p = (float4*)y;
    for (size_t i = idx; i < n4; i += stride) {
        int o = (int)((i >> 10) & 255);
        float a = cA[o], c = cB[o];
        float4 v = p[i];
        v.x = fmaxf(fmaf(a, v.x, c), 0.0f);
        v.y = fmaxf(fmaf(a, v.y, c), 0.0f);
        v.z = fmaxf(fmaf(a, v.z, c), 0.0f);
        v.w = fmaxf(fmaf(a, v.w, c), 0.0f);
        p[i] = v;
    }
}

// ---------------------------------------------------------------------------
extern "C" void kernel_launch(void* const* d_in, const int* in_sizes, int n_in,
                              void* d_out, int out_size, void* d_ws, size_t ws_size,
                              hipStream_t stream) {
    const float* xyzl  = (const float*)d_in[0];
    const float* xyzh  = (const float*)d_in[1];
    const float* flow  = (const float*)d_in[2];
    const float* fhigh = (const float*)d_in[3];
    const float* W     = (const float*)d_in[4];
    const float* bias  = (const float*)d_in[5];
    const float* gamma = (const float*)d_in[6];
    const float* beta  = (const float*)d_in[7];
    float* out = (float*)d_out;
    char*  ws  = (char*)d_ws;
    (void)in_sizes; (void)n_in; (void)out_size; (void)ws_size;

    // ws layout (bytes); FLT overlays FHT (FHT dead after gemm1)
    float*          w3    = (float*)(ws + 0);                  //  0.79 MB
    int*            idx3  = (int*)  (ws + 786432);             //  0.79 MB
    float*          gt    = (float*)(ws + 1572864);            // 16 MB
    unsigned short* fht   = (unsigned short*)(ws + 18350080);  // 8 MB (shared region)
    unsigned short* flt   = (unsigned short*)(ws + 18350080);  // 16 MB (overlay after gemm1)
    unsigned short* w1    = (unsigned short*)(ws + 35127296);  // 128 KB
    unsigned short* w2    = (unsigned short*)(ws + 35258368);  // 64 KB
    float*          ps    = (float*)(ws + 35323904);           // 1 MB
    float*          pq    = (float*)(ws + 36372480);           // 1 MB
    float*          cA    = (float*)(ws + 37421056);
    float*          cB    = (float*)(ws + 37422080);
    float4*         cand  = (float4*)(ws + 37423104);          // 256 KB

    hipLaunchKernelGGL(k_prep_w,    dim3(256),             dim3(384), 0, stream, W, w1, w2);
    hipLaunchKernelGGL(k_prep_cand, dim3(kB),              dim3(256), 0, stream, xyzh, cand);
    hipLaunchKernelGGL(k_prep_fht,  dim3(16, 4, kB),       dim3(256), 0, stream, fhigh, fht);
    hipLaunchKernelGGL(k_three_nn,  dim3(kNL / 64, kB),    dim3(256), 0, stream, xyzl, cand, w3, idx3);
    hipLaunchKernelGGL(k_gemm1,     dim3(kNH / 64, kB),    dim3(256), 0, stream, fht, w1, gt);
    hipLaunchKernelGGL(k_prep_flt,  dim3(kNL / 64, 2, kB), dim3(256), 0, stream, flow, flt);
    hipLaunchKernelGGL(k_gemm2,     dim3(kNL / 64, kB),    dim3(256), 0, stream,
                       flt, w2, gt, bias, w3, idx3, out, ps, pq);
    hipLaunchKernelGGL(k_finalize,  dim3(256),             dim3(256), 0, stream, ps, pq, gamma, beta, cA, cB);
    hipLaunchKernelGGL(k_apply,     dim3(2048),            dim3(256), 0, stream, out, cA, cB);
}

// Round 4
// 138.227 us; speedup vs baseline: 2.9695x; 1.1298x over previous
//
#include <hip/hip_runtime.h>
#include <math.h>

constexpr int kB   = 16;
constexpr int kNL  = 4096;
constexpr int kNH  = 1024;
constexpr int kCL  = 128;
constexpr int kCH  = 256;
constexpr int kOUT = 256;

typedef __attribute__((ext_vector_type(8))) short s16x8;
typedef __attribute__((ext_vector_type(8))) unsigned short u16x8;
typedef __attribute__((ext_vector_type(4))) unsigned short u16x4;
typedef __attribute__((ext_vector_type(4))) float f32x4;

__device__ __forceinline__ unsigned short f2bf(float x) {
    unsigned int u = __float_as_uint(x);
    return (unsigned short)((u + 0x7FFFu + ((u >> 16) & 1u)) >> 16);
}
__device__ __forceinline__ float bf2f(unsigned short h) {
    return __uint_as_float((unsigned int)h << 16);
}

// ---------------------------------------------------------------------------
// W (256x384 f32) -> W1bf (256x256 bf16), W2bf (256x128 bf16)
// ---------------------------------------------------------------------------
__global__ void k_prep_w(const float* __restrict__ W, unsigned short* __restrict__ w1,
                         unsigned short* __restrict__ w2) {
    int o = blockIdx.x, k = threadIdx.x;
    float v = W[o * 384 + k];
    if (k < kCH) w1[o * kCH + k] = f2bf(v);
    else         w2[o * kCL + (k - kCH)] = f2bf(v);
}

// feat_high (B,CH,NH) f32 -> FHT_bf (B,NH,CH) bf16
__global__ void k_prep_fht(const float* __restrict__ fh, unsigned short* __restrict__ fht) {
    __shared__ float tile[64][65];
    int b = blockIdx.z, j0 = blockIdx.x * 64, c0 = blockIdx.y * 64;
    const float* src = fh + (size_t)b * kCH * kNH;
    unsigned short* dst = fht + (size_t)b * kNH * kCH;
    #pragma unroll
    for (int i = 0; i < 16; ++i) {
        int e = threadIdx.x + i * 256, c = e >> 6, j = e & 63;
        tile[c][j] = src[(size_t)(c0 + c) * kNH + j0 + j];
    }
    __syncthreads();
    #pragma unroll
    for (int i = 0; i < 16; ++i) {
        int e = threadIdx.x + i * 256, j = e >> 6, c = e & 63;
        dst[(size_t)(j0 + j) * kCH + c0 + c] = f2bf(tile[c][j]);
    }
}

// feat_low (B,CL,NL) f32 -> FLT_bf (B,NL,CL) bf16
__global__ void k_prep_flt(const float* __restrict__ fl, unsigned short* __restrict__ flt) {
    __shared__ float tile[64][65];
    int b = blockIdx.z, n0 = blockIdx.x * 64, c0 = blockIdx.y * 64;
    const float* src = fl + (size_t)b * kCL * kNL;
    unsigned short* dst = flt + (size_t)b * kNL * kCL;
    #pragma unroll
    for (int i = 0; i < 16; ++i) {
        int e = threadIdx.x + i * 256, c = e >> 6, n = e & 63;
        tile[c][n] = src[(size_t)(c0 + c) * kNL + n0 + n];
    }
    __syncthreads();
    #pragma unroll
    for (int i = 0; i < 16; ++i) {
        int e = threadIdx.x + i * 256, n = e >> 6, c = e & 63;
        dst[(size_t)(n0 + n) * kCL + c0 + c] = f2bf(tile[c][n]);
    }
}

// ---------------------------------------------------------------------------
// cand[b][j] = {2x, 2y, 2z, x^2+y^2+z^2}; pre-doubling is fp-exact.
// ---------------------------------------------------------------------------
__global__ void k_prep_cand(const float* __restrict__ xyzh, float4* __restrict__ cand) {
    int b = blockIdx.x;
    const float* H = xyzh + (size_t)b * kNH * 3;
    for (int j = threadIdx.x; j < kNH; j += 256) {
        float xx = H[j * 3 + 0], yy = H[j * 3 + 1], zz = H[j * 3 + 2];
        float s = __fmul_rn(xx, xx);
        s = __fadd_rn(s, __fmul_rn(yy, yy));
        s = __fadd_rn(s, __fmul_rn(zz, zz));
        cand[(size_t)b * kNH + j] = make_float4(xx + xx, yy + yy, zz + zz, s);
    }
}

// ---------------------------------------------------------------------------
// three_nn: wave-uniform scalar candidate loads, branchless 3-deep insert,
// 4 threads/point j-split + lexicographic (d, idx) merge (= top_k ties).
// ---------------------------------------------------------------------------
__global__ __launch_bounds__(256) void k_three_nn(
    const float* __restrict__ xyzl, const float4* __restrict__ cand,
    float* __restrict__ w3, int* __restrict__ idx3)
{
    __shared__ float md[64][4][3];
    __shared__ int   midx[64][4][3];
    int b = blockIdx.y, t = threadIdx.x;
    int sub = t >> 6, ll = t & 63;
    int l = blockIdx.x * 64 + ll;

    const float* L = xyzl + ((size_t)b * kNL + l) * 3;
    float x = L[0], y = L[1], z = L[2];
    float sql = __fmul_rn(x, x);
    sql = __fadd_rn(sql, __fmul_rn(y, y));
    sql = __fadd_rn(sql, __fmul_rn(z, z));

    float d0 = 1e30f, d1 = 1e30f, d2 = 1e30f;
    int   i0 = 0,     i1 = 0,     i2 = 0;

    int jbeg = __builtin_amdgcn_readfirstlane(sub << 8);
    const float4* C = cand + ((size_t)b << 10) + jbeg;
    #pragma unroll 8
    for (int jj = 0; jj < 256; ++jj) {
        float4 c = C[jj];
        float inner2 = __fmul_rn(x, c.x);
        inner2 = __fadd_rn(inner2, __fmul_rn(y, c.y));
        inner2 = __fadd_rn(inner2, __fmul_rn(z, c.z));
        float dsq = __fsub_rn(__fadd_rn(sql, c.w), inner2);
        dsq = fmaxf(dsq, 0.0f);
        int j = jbeg + jj;
        bool c0 = dsq < d0, c1 = dsq < d1, c2 = dsq < d2;
        float td = c1 ? d1 : dsq;  int ti = c1 ? i1 : j;
        d2 = c2 ? td : d2;         i2 = c2 ? ti : i2;
        td = c0 ? d0 : dsq;        ti = c0 ? i0 : j;
        d1 = c1 ? td : d1;         i1 = c1 ? ti : i1;
        d0 = c0 ? dsq : d0;        i0 = c0 ? j : i0;
    }

    md[ll][sub][0] = d0;  md[ll][sub][1] = d1;  md[ll][sub][2] = d2;
    midx[ll][sub][0] = i0; midx[ll][sub][1] = i1; midx[ll][sub][2] = i2;
    __syncthreads();

    if (sub == 0) {
        float e0 = 1e30f, e1 = 1e30f, e2 = 1e30f;
        int   a0 = 0x7fffffff, a1 = 0x7fffffff, a2 = 0x7fffffff;
        #pragma unroll
        for (int s = 0; s < 4; ++s) {
            #pragma unroll
            for (int k = 0; k < 3; ++k) {
                float d = md[ll][s][k]; int ii = midx[ll][s][k];
                bool lt2 = (d < e2) || (d == e2 && ii < a2);
                if (lt2) {
                    bool lt0 = (d < e0) || (d == e0 && ii < a0);
                    bool lt1 = (d < e1) || (d == e1 && ii < a1);
                    if (lt0)      { e2 = e1; a2 = a1; e1 = e0; a1 = a0; e0 = d; a0 = ii; }
                    else if (lt1) { e2 = e1; a2 = a1; e1 = d; a1 = ii; }
                    else          { e2 = d; a2 = ii; }
                }
            }
        }
        float q0 = fmaxf(sqrtf(e0), 1e-8f);
        float q1 = fmaxf(sqrtf(e1), 1e-8f);
        float q2 = fmaxf(sqrtf(e2), 1e-8f);
        float r0 = 1.0f / q0, r1 = 1.0f / q1, r2 = 1.0f / q2;
        float s = __fadd_rn(__fadd_rn(r0, r1), r2);
        size_t base = ((size_t)b * kNL + l) * 3;
        w3[base + 0] = r0 / s;  w3[base + 1] = r1 / s;  w3[base + 2] = r2 / s;
        idx3[base + 0] = a0;    idx3[base + 1] = a1;    idx3[base + 2] = a2;
    }
}

// ---------------------------------------------------------------------------
// GEMM1: G = W1 x feat_high per batch -> gtb bf16, FRAGMENT-PERMUTED layout:
// position [w][hi][mi][r] holds channel o = 64w+16mi+4hi+r. This makes the
// 16 channels a gemm2 thread gathers one contiguous 32B slice.
// ---------------------------------------------------------------------------
__global__ __launch_bounds__(256, 4) void k_gemm1(
    const unsigned short* __restrict__ fht, const unsigned short* __restrict__ w1,
    unsigned short* __restrict__ gtb)
{
    __shared__ __align__(16) unsigned short Bt[64][264];
    int b = blockIdx.y, j0 = blockIdx.x * 64, t = threadIdx.x;
    const unsigned short* src = fht + ((size_t)b * kNH + j0) * kCH;
    #pragma unroll
    for (int i = 0; i < 8; ++i) {
        int e = t + i * 256, j = e >> 5, u = e & 31;
        *(s16x8*)(&Bt[j][u * 8]) = *(const s16x8*)(src + (size_t)j * kCH + u * 8);
    }
    __syncthreads();

    int w = t >> 6, lane = t & 63, lo = lane & 15, hi = lane >> 4;
    f32x4 vz = {0.f, 0.f, 0.f, 0.f};
    f32x4 acc[4][4];
    #pragma unroll
    for (int mi = 0; mi < 4; ++mi)
        #pragma unroll
        for (int ni = 0; ni < 4; ++ni) acc[mi][ni] = vz;

    #pragma unroll
    for (int ks = 0; ks < 8; ++ks) {
        s16x8 av[4], bv[4];
        #pragma unroll
        for (int mi = 0; mi < 4; ++mi)
            av[mi] = *(const s16x8*)(w1 + (size_t)(64 * w + 16 * mi + lo) * kCH + ks * 32 + hi * 8);
        #pragma unroll
        for (int ni = 0; ni < 4; ++ni)
            bv[ni] = *(const s16x8*)(&Bt[16 * ni + lo][ks * 32 + hi * 8]);
        #pragma unroll
        for (int mi = 0; mi < 4; ++mi)
            #pragma unroll
            for (int ni = 0; ni < 4; ++ni)
                acc[mi][ni] = __builtin_amdgcn_mfma_f32_16x16x32_bf16(av[mi], bv[ni], acc[mi][ni], 0, 0, 0);
    }

    unsigned short* G = gtb + ((size_t)b * kNH + j0) * kOUT;
    #pragma unroll
    for (int mi = 0; mi < 4; ++mi)
        #pragma unroll
        for (int ni = 0; ni < 4; ++ni) {
            f32x4 a = acc[mi][ni];
            u16x4 h;
            #pragma unroll
            for (int r = 0; r < 4; ++r) h[r] = f2bf(a[r]);
            // permuted position: w*64 + hi*16 + mi*4 + r
            *(u16x4*)(&G[(size_t)(16 * ni + lo) * kOUT + w * 64 + hi * 16 + mi * 4]) = h;
        }
}

// ---------------------------------------------------------------------------
// GEMM2 + gather + bias + fused partial BN stats.
// Gather: per k-neighbor, 8 independent 16B loads staged in registers FIRST,
// then convert+FMA (3 latency hops instead of 48). LDS = 19 KB.
// ---------------------------------------------------------------------------
__global__ __launch_bounds__(256, 4) void k_gemm2(
    const unsigned short* __restrict__ flt, const unsigned short* __restrict__ w2,
    const unsigned short* __restrict__ gtb, const float* __restrict__ bias,
    const float* __restrict__ w3, const int* __restrict__ idx3,
    float* __restrict__ y, float* __restrict__ ps, float* __restrict__ pq)
{
    __shared__ __align__(16) char smem[17408];             // union: Bt | red
    unsigned short (*Bt)[136] = (unsigned short (*)[136])smem;
    float* red = (float*)smem;                             // [256][17]
    __shared__ float wc[64][3];
    __shared__ int   ic[64][3];

    int b = blockIdx.y, n0 = blockIdx.x * 64, t = threadIdx.x;
    int blin = b * gridDim.x + blockIdx.x;

    if (t < 192) {
        int n = t / 3, k = t - n * 3;
        wc[n][k] = w3[((size_t)b * kNL + n0 + n) * 3 + k];
        ic[n][k] = idx3[((size_t)b * kNL + n0 + n) * 3 + k];
    }
    const unsigned short* src = flt + ((size_t)b * kNL + n0) * kCL;
    #pragma unroll
    for (int i = 0; i < 4; ++i) {
        int e = t + i * 256, n = e >> 4, u = e & 15;
        *(s16x8*)(&Bt[n][u * 8]) = *(const s16x8*)(src + (size_t)n * kCL + u * 8);
    }
    __syncthreads();

    int w = t >> 6, lane = t & 63, lo = lane & 15, hi = lane >> 4;
    f32x4 vz = {0.f, 0.f, 0.f, 0.f};
    f32x4 acc[4][4];
    #pragma unroll
    for (int mi = 0; mi < 4; ++mi)
        #pragma unroll
        for (int ni = 0; ni < 4; ++ni) acc[mi][ni] = vz;

    #pragma unroll
    for (int ks = 0; ks < 4; ++ks) {
        s16x8 av[4], bv[4];
        #pragma unroll
        for (int mi = 0; mi < 4; ++mi)
            av[mi] = *(const s16x8*)(w2 + (size_t)(64 * w + 16 * mi + lo) * kCL + ks * 32 + hi * 8);
        #pragma unroll
        for (int ni = 0; ni < 4; ++ni)
            bv[ni] = *(const s16x8*)(&Bt[16 * ni + lo][ks * 32 + hi * 8]);
        #pragma unroll
        for (int mi = 0; mi < 4; ++mi)
            #pragma unroll
            for (int ni = 0; ni < 4; ++ni)
                acc[mi][ni] = __builtin_amdgcn_mfma_f32_16x16x32_bf16(av[mi], bv[ni], acc[mi][ni], 0, 0, 0);
    }

    // gather: for each neighbor k, stage 8 loads (4 ni x 2 halves), then FMA
    const unsigned short* Gb = gtb + (size_t)b * kNH * kOUT + w * 64 + hi * 16;
    #pragma unroll
    for (int k = 0; k < 3; ++k) {
        u16x8 g0[4], g1[4];
        float wcr[4];
        #pragma unroll
        for (int ni = 0; ni < 4; ++ni) {
            int lc = 16 * ni + lo;
            int jj = ic[lc][k];
            wcr[ni] = wc[lc][k];
            const u16x8* p = (const u16x8*)(Gb + (size_t)jj * kOUT);
            g0[ni] = p[0];
            g1[ni] = p[1];
        }
        #pragma unroll
        for (int ni = 0; ni < 4; ++ni) {
            float wg = wcr[ni];
            #pragma unroll
            for (int r = 0; r < 4; ++r) {
                acc[0][ni][r] = fmaf(wg, bf2f(g0[ni][r]),     acc[0][ni][r]);
                acc[1][ni][r] = fmaf(wg, bf2f(g0[ni][4 + r]), acc[1][ni][r]);
                acc[2][ni][r] = fmaf(wg, bf2f(g1[ni][r]),     acc[2][ni][r]);
                acc[3][ni][r] = fmaf(wg, bf2f(g1[ni][4 + r]), acc[3][ni][r]);
            }
        }
    }
    #pragma unroll
    for (int mi = 0; mi < 4; ++mi) {
        f32x4 bb = *(const f32x4*)(bias + 64 * w + 16 * mi + 4 * hi);
        #pragma unroll
        for (int ni = 0; ni < 4; ++ni) acc[mi][ni] += bb;
    }

    // store y (f32)
    float* Y = y + (size_t)b * kOUT * kNL + n0;
    #pragma unroll
    for (int mi = 0; mi < 4; ++mi)
        #pragma unroll
        for (int ni = 0; ni < 4; ++ni)
            #pragma unroll
            for (int r = 0; r < 4; ++r)
                Y[(size_t)(64 * w + 16 * mi + 4 * hi + r) * kNL + 16 * ni + lo] = acc[mi][ni][r];

    // fused partial BN stats, two rounds through the 17-KB red table
    int ow = t >> 6, omi = (t >> 4) & 3, ohi = (t >> 2) & 3, orr = t & 3;
    __syncthreads();   // Bt dead
    #pragma unroll
    for (int mi = 0; mi < 4; ++mi) {
        f32x4 s = acc[mi][0] + acc[mi][1] + acc[mi][2] + acc[mi][3];
        #pragma unroll
        for (int r = 0; r < 4; ++r) red[t * 17 + mi * 4 + r] = s[r];
    }
    __syncthreads();
    float ssum = 0.0f;
    #pragma unroll
    for (int l2 = 0; l2 < 16; ++l2)
        ssum += red[(ow * 64 + ohi * 16 + l2) * 17 + omi * 4 + orr];
    __syncthreads();
    #pragma unroll
    for (int mi = 0; mi < 4; ++mi) {
        f32x4 q = acc[mi][0] * acc[mi][0] + acc[mi][1] * acc[mi][1]
                + acc[mi][2] * acc[mi][2] + acc[mi][3] * acc[mi][3];
        #pragma unroll
        for (int r = 0; r < 4; ++r) red[t * 17 + mi * 4 + r] = q[r];
    }
    __syncthreads();
    float qsum = 0.0f;
    #pragma unroll
    for (int l2 = 0; l2 < 16; ++l2)
        qsum += red[(ow * 64 + ohi * 16 + l2) * 17 + omi * 4 + orr];

    ps[(size_t)t * 1024 + blin] = ssum;
    pq[(size_t)t * 1024 + blin] = qsum;
}

// ---------------------------------------------------------------------------
__global__ void k_finalize(const float* __restrict__ ps, const float* __restrict__ pq,
                           const float* __restrict__ gamma, const float* __restrict__ beta,
                           float* __restrict__ cA, float* __restrict__ cB) {
    int o = blockIdx.x, t = threadIdx.x;
    float s = 0.0f, q = 0.0f;
    #pragma unroll
    for (int i = 0; i < 4; ++i) {
        s += ps[(size_t)o * 1024 + t + i * 256];
        q += pq[(size_t)o * 1024 + t + i * 256];
    }
    #pragma unroll
    for (int off = 32; off > 0; off >>= 1) {
        s += __shfl_down(s, off);
        q += __shfl_down(q, off);
    }
    __shared__ float ls[4], lq[4];
    if ((t & 63) == 0) { ls[t >> 6] = s; lq[t >> 6] = q; }
    __syncthreads();
    if (t == 0) {
        s = ls[0] + ls[1] + ls[2] + ls[3];
        q = lq[0] + lq[1] + lq[2] + lq[3];
        const float inv = 1.0f / (float)(kB * kNL);
        float mean = s * inv;
        float var  = q * inv - mean * mean;
        float a = gamma[o] * rsqrtf(var + 1e-5f);
        cA[o] = a;
        cB[o] = beta[o] - mean * a;
    }
}

// ---------------------------------------------------------------------------
__global__ void k_apply(float* __restrict__ y, const float* __restrict__ cA,
                        const float* __restrict__ cB) {
    size_t idx    = (size_t)blockIdx.x * 256 + threadIdx.x;
    size_t stride = (size_t)gridDim.x * 256;
    const size_t n4 = (size_t)kB * kOUT * kNL / 4;
    float4* p = (float4*)y;
    for (size_t i = idx; i < n4; i += stride) {
        int o = (int)((i >> 10) & 255);
        float a = cA[o], c = cB[o];
        float4 v = p[i];
        v.x = fmaxf(fmaf(a, v.x, c), 0.0f);
        v.y = fmaxf(fmaf(a, v.y, c), 0.0f);
        v.z = fmaxf(fmaf(a, v.z, c), 0.0f);
        v.w = fmaxf(fmaf(a, v.w, c), 0.0f);
        p[i] = v;
    }
}

// ---------------------------------------------------------------------------
extern "C" void kernel_launch(void* const* d_in, const int* in_sizes, int n_in,
                              void* d_out, int out_size, void* d_ws, size_t ws_size,
                              hipStream_t stream) {
    const float* xyzl  = (const float*)d_in[0];
    const float* xyzh  = (const float*)d_in[1];
    const float* flow  = (const float*)d_in[2];
    const float* fhigh = (const float*)d_in[3];
    const float* W     = (const float*)d_in[4];
    const float* bias  = (const float*)d_in[5];
    const float* gamma = (const float*)d_in[6];
    const float* beta  = (const float*)d_in[7];
    float* out = (float*)d_out;
    char*  ws  = (char*)d_ws;
    (void)in_sizes; (void)n_in; (void)out_size; (void)ws_size;

    // ws layout (bytes); FLT overlays FHT (fht dead after gemm1; prep_flt runs after)
    float*          w3   = (float*)(ws + 0);                   // 786432
    int*            idx3 = (int*)  (ws + 786432);              // 786432
    unsigned short* gtb  = (unsigned short*)(ws + 1572864);    // 8 MB (bf16, permuted)
    unsigned short* fht  = (unsigned short*)(ws + 9961472);    // 8 MB
    unsigned short* flt  = (unsigned short*)(ws + 9961472);    // 16 MB (overlay)
    unsigned short* w1   = (unsigned short*)(ws + 26738688);   // 128 KB
    unsigned short* w2   = (unsigned short*)(ws + 26869760);   // 64 KB
    float*          ps   = (float*)(ws + 26935296);            // 1 MB
    float*          pq   = (float*)(ws + 27983872);            // 1 MB
    float*          cA   = (float*)(ws + 29032448);            // 1 KB
    float*          cB   = (float*)(ws + 29033472);            // 1 KB
    float4*         cand = (float4*)(ws + 29034496);           // 256 KB

    hipLaunchKernelGGL(k_prep_w,    dim3(256),             dim3(384), 0, stream, W, w1, w2);
    hipLaunchKernelGGL(k_prep_cand, dim3(kB),              dim3(256), 0, stream, xyzh, cand);
    hipLaunchKernelGGL(k_prep_fht,  dim3(16, 4, kB),       dim3(256), 0, stream, fhigh, fht);
    hipLaunchKernelGGL(k_three_nn,  dim3(kNL / 64, kB),    dim3(256), 0, stream, xyzl, cand, w3, idx3);
    hipLaunchKernelGGL(k_gemm1,     dim3(kNH / 64, kB),    dim3(256), 0, stream, fht, w1, gtb);
    hipLaunchKernelGGL(k_prep_flt,  dim3(kNL / 64, 2, kB), dim3(256), 0, stream, flow, flt);
    hipLaunchKernelGGL(k_gemm2,     dim3(kNL / 64, kB),    dim3(256), 0, stream,
                       flt, w2, gtb, bias, w3, idx3, out, ps, pq);
    hipLaunchKernelGGL(k_finalize,  dim3(256),             dim3(256), 0, stream, ps, pq, gamma, beta, cA, cB);
    hipLaunchKernelGGL(k_apply,     dim3(2048),            dim3(256), 0, stream, out, cA, cB);
}

// Round 5
// 121.861 us; speedup vs baseline: 3.3683x; 1.1343x over previous
//
#include <hip/hip_runtime.h>
#include <math.h>

constexpr int kB   = 16;
constexpr int kNL  = 4096;
constexpr int kNH  = 1024;
constexpr int kCL  = 128;
constexpr int kCH  = 256;
constexpr int kOUT = 256;

typedef __attribute__((ext_vector_type(8))) short s16x8;
typedef __attribute__((ext_vector_type(8))) unsigned short u16x8;
typedef __attribute__((ext_vector_type(4))) unsigned short u16x4;
typedef __attribute__((ext_vector_type(4))) float f32x4;

__device__ __forceinline__ unsigned short f2bf(float x) {
    unsigned int u = __float_as_uint(x);
    return (unsigned short)((u + 0x7FFFu + ((u >> 16) & 1u)) >> 16);
}
__device__ __forceinline__ unsigned int f2bf_pk(float a, float b) {
    return (unsigned int)f2bf(a) | ((unsigned int)f2bf(b) << 16);
}
__device__ __forceinline__ float bf2f(unsigned short h) {
    return __uint_as_float((unsigned int)h << 16);
}

// ---------------------------------------------------------------------------
// W (256x384 f32) -> W1bf (256x256 bf16), W2bf (256x128 bf16)
// ---------------------------------------------------------------------------
__global__ void k_prep_w(const float* __restrict__ W, unsigned short* __restrict__ w1,
                         unsigned short* __restrict__ w2) {
    int o = blockIdx.x, k = threadIdx.x;
    float v = W[o * 384 + k];
    if (k < kCH) w1[o * kCH + k] = f2bf(v);
    else         w2[o * kCL + (k - kCH)] = f2bf(v);
}

// ---------------------------------------------------------------------------
// cand[b][j] = {2x, 2y, 2z, x^2+y^2+z^2}; pre-doubling is fp-exact.
// ---------------------------------------------------------------------------
__global__ void k_prep_cand(const float* __restrict__ xyzh, float4* __restrict__ cand) {
    int b = blockIdx.x;
    const float* H = xyzh + (size_t)b * kNH * 3;
    for (int j = threadIdx.x; j < kNH; j += 256) {
        float xx = H[j * 3 + 0], yy = H[j * 3 + 1], zz = H[j * 3 + 2];
        float s = __fmul_rn(xx, xx);
        s = __fadd_rn(s, __fmul_rn(yy, yy));
        s = __fadd_rn(s, __fmul_rn(zz, zz));
        cand[(size_t)b * kNH + j] = make_float4(xx + xx, yy + yy, zz + zz, s);
    }
}

// ---------------------------------------------------------------------------
// three_nn v5: 512-thread blocks, 8 wave-uniform j-subranges per point
// (100% occupancy), 2 independent insert streams per thread (ILP), exact
// fp32 distances via wave-uniform scalar loads. All merges lex-(d,idx)
// = jax.lax.top_k tie semantics.
// ---------------------------------------------------------------------------
__global__ __launch_bounds__(512) void k_three_nn(
    const float* __restrict__ xyzl, const float4* __restrict__ cand,
    float* __restrict__ w3, int* __restrict__ idx3)
{
    __shared__ float md[64][8][3];
    __shared__ int   midx[64][8][3];
    int b = blockIdx.y, t = threadIdx.x;
    int sub = t >> 6, ll = t & 63;          // sub is wave-uniform
    int l = blockIdx.x * 64 + ll;

    const float* L = xyzl + ((size_t)b * kNL + l) * 3;
    float x = L[0], y = L[1], z = L[2];
    float sql = __fmul_rn(x, x);
    sql = __fadd_rn(sql, __fmul_rn(y, y));
    sql = __fadd_rn(sql, __fmul_rn(z, z));

    float dA0 = 1e30f, dA1 = 1e30f, dA2 = 1e30f;
    int   iA0 = 0,     iA1 = 0,     iA2 = 0;
    float dB0 = 1e30f, dB1 = 1e30f, dB2 = 1e30f;
    int   iB0 = 0,     iB1 = 0,     iB2 = 0;

    int jbeg = __builtin_amdgcn_readfirstlane(sub << 7);   // 128 candidates/sub
    const float4* C = cand + ((size_t)b << 10) + jbeg;

    #pragma unroll 4
    for (int jj = 0; jj < 64; ++jj) {
        {   // stream A: candidates [jbeg, jbeg+64)
            float4 c = C[jj];
            float inner2 = __fmul_rn(x, c.x);
            inner2 = __fadd_rn(inner2, __fmul_rn(y, c.y));
            inner2 = __fadd_rn(inner2, __fmul_rn(z, c.z));
            float dsq = __fsub_rn(__fadd_rn(sql, c.w), inner2);
            dsq = fmaxf(dsq, 0.0f);
            int j = jbeg + jj;
            bool c0 = dsq < dA0, c1 = dsq < dA1, c2 = dsq < dA2;
            float td = c1 ? dA1 : dsq;  int ti = c1 ? iA1 : j;
            dA2 = c2 ? td : dA2;        iA2 = c2 ? ti : iA2;
            td = c0 ? dA0 : dsq;        ti = c0 ? iA0 : j;
            dA1 = c1 ? td : dA1;        iA1 = c1 ? ti : iA1;
            dA0 = c0 ? dsq : dA0;       iA0 = c0 ? j : iA0;
        }
        {   // stream B: candidates [jbeg+64, jbeg+128)
            float4 c = C[64 + jj];
            float inner2 = __fmul_rn(x, c.x);
            inner2 = __fadd_rn(inner2, __fmul_rn(y, c.y));
            inner2 = __fadd_rn(inner2, __fmul_rn(z, c.z));
            float dsq = __fsub_rn(__fadd_rn(sql, c.w), inner2);
            dsq = fmaxf(dsq, 0.0f);
            int j = jbeg + 64 + jj;
            bool c0 = dsq < dB0, c1 = dsq < dB1, c2 = dsq < dB2;
            float td = c1 ? dB1 : dsq;  int ti = c1 ? iB1 : j;
            dB2 = c2 ? td : dB2;        iB2 = c2 ? ti : iB2;
            td = c0 ? dB0 : dsq;        ti = c0 ? iB0 : j;
            dB1 = c1 ? td : dB1;        iB1 = c1 ? ti : iB1;
            dB0 = c0 ? dsq : dB0;       iB0 = c0 ? j : iB0;
        }
    }

    // merge stream B into A (lex (d,idx); B entries sorted ascending)
    #pragma unroll
    for (int m = 0; m < 3; ++m) {
        float d = (m == 0) ? dB0 : (m == 1) ? dB1 : dB2;
        int  ii = (m == 0) ? iB0 : (m == 1) ? iB1 : iB2;
        bool lt2 = (d < dA2) || (d == dA2 && ii < iA2);
        if (lt2) {
            bool lt0 = (d < dA0) || (d == dA0 && ii < iA0);
            bool lt1 = (d < dA1) || (d == dA1 && ii < iA1);
            if (lt0)      { dA2 = dA1; iA2 = iA1; dA1 = dA0; iA1 = iA0; dA0 = d; iA0 = ii; }
            else if (lt1) { dA2 = dA1; iA2 = iA1; dA1 = d; iA1 = ii; }
            else          { dA2 = d; iA2 = ii; }
        }
    }

    md[ll][sub][0] = dA0;  md[ll][sub][1] = dA1;  md[ll][sub][2] = dA2;
    midx[ll][sub][0] = iA0; midx[ll][sub][1] = iA1; midx[ll][sub][2] = iA2;
    __syncthreads();

    if (sub == 0) {
        float e0 = 1e30f, e1 = 1e30f, e2 = 1e30f;
        int   a0 = 0x7fffffff, a1 = 0x7fffffff, a2 = 0x7fffffff;
        #pragma unroll
        for (int s = 0; s < 8; ++s) {
            #pragma unroll
            for (int k = 0; k < 3; ++k) {
                float d = md[ll][s][k]; int ii = midx[ll][s][k];
                bool lt2 = (d < e2) || (d == e2 && ii < a2);
                if (lt2) {
                    bool lt0 = (d < e0) || (d == e0 && ii < a0);
                    bool lt1 = (d < e1) || (d == e1 && ii < a1);
                    if (lt0)      { e2 = e1; a2 = a1; e1 = e0; a1 = a0; e0 = d; a0 = ii; }
                    else if (lt1) { e2 = e1; a2 = a1; e1 = d; a1 = ii; }
                    else          { e2 = d; a2 = ii; }
                }
            }
        }
        float q0 = fmaxf(sqrtf(e0), 1e-8f);
        float q1 = fmaxf(sqrtf(e1), 1e-8f);
        float q2 = fmaxf(sqrtf(e2), 1e-8f);
        float r0 = 1.0f / q0, r1 = 1.0f / q1, r2 = 1.0f / q2;
        float s = __fadd_rn(__fadd_rn(r0, r1), r2);
        size_t base = ((size_t)b * kNL + l) * 3;
        w3[base + 0] = r0 / s;  w3[base + 1] = r1 / s;  w3[base + 2] = r2 / s;
        idx3[base + 0] = a0;    idx3[base + 1] = a1;    idx3[base + 2] = a2;
    }
}

// ---------------------------------------------------------------------------
// GEMM1: G = W1 x feat_high per batch. Reads fhigh f32 DIRECTLY (no prep
// pass), converts to bf16 while staging into LDS. Output gtb bf16 in the
// fragment-permuted layout [w][hi][mi][r] (channel o = 64w+16mi+4hi+r).
// ---------------------------------------------------------------------------
__global__ __launch_bounds__(256, 4) void k_gemm1(
    const float* __restrict__ fhigh, const unsigned short* __restrict__ w1,
    unsigned short* __restrict__ gtb)
{
    __shared__ __align__(16) unsigned short Bt[64][264];
    int b = blockIdx.y, j0 = blockIdx.x * 64, t = threadIdx.x;
    const float* src = fhigh + (size_t)b * kCH * kNH + j0;
    // 128 c-pairs x 16 j4-groups, 8 units/thread
    #pragma unroll
    for (int i = 0; i < 8; ++i) {
        int e = t + i * 256, cp = e >> 4, j4 = e & 15;
        f32x4 a  = *(const f32x4*)(src + (size_t)(2 * cp)     * kNH + 4 * j4);
        f32x4 b2 = *(const f32x4*)(src + (size_t)(2 * cp + 1) * kNH + 4 * j4);
        #pragma unroll
        for (int r = 0; r < 4; ++r)
            *(unsigned int*)(&Bt[4 * j4 + r][2 * cp]) = f2bf_pk(a[r], b2[r]);
    }
    __syncthreads();

    int w = t >> 6, lane = t & 63, lo = lane & 15, hi = lane >> 4;
    f32x4 vz = {0.f, 0.f, 0.f, 0.f};
    f32x4 acc[4][4];
    #pragma unroll
    for (int mi = 0; mi < 4; ++mi)
        #pragma unroll
        for (int ni = 0; ni < 4; ++ni) acc[mi][ni] = vz;

    #pragma unroll
    for (int ks = 0; ks < 8; ++ks) {
        s16x8 av[4], bv[4];
        #pragma unroll
        for (int mi = 0; mi < 4; ++mi)
            av[mi] = *(const s16x8*)(w1 + (size_t)(64 * w + 16 * mi + lo) * kCH + ks * 32 + hi * 8);
        #pragma unroll
        for (int ni = 0; ni < 4; ++ni)
            bv[ni] = *(const s16x8*)(&Bt[16 * ni + lo][ks * 32 + hi * 8]);
        #pragma unroll
        for (int mi = 0; mi < 4; ++mi)
            #pragma unroll
            for (int ni = 0; ni < 4; ++ni)
                acc[mi][ni] = __builtin_amdgcn_mfma_f32_16x16x32_bf16(av[mi], bv[ni], acc[mi][ni], 0, 0, 0);
    }

    unsigned short* G = gtb + ((size_t)b * kNH + j0) * kOUT;
    #pragma unroll
    for (int mi = 0; mi < 4; ++mi)
        #pragma unroll
        for (int ni = 0; ni < 4; ++ni) {
            f32x4 a = acc[mi][ni];
            u16x4 h;
            #pragma unroll
            for (int r = 0; r < 4; ++r) h[r] = f2bf(a[r]);
            *(u16x4*)(&G[(size_t)(16 * ni + lo) * kOUT + w * 64 + hi * 16 + mi * 4]) = h;
        }
}

// ---------------------------------------------------------------------------
// GEMM2 + gather + bias + fused partial BN stats. Reads feat_low f32
// DIRECTLY (no prep pass); writes y as bf16 (stats from f32 accs).
// ---------------------------------------------------------------------------
__global__ __launch_bounds__(256, 4) void k_gemm2(
    const float* __restrict__ flow, const unsigned short* __restrict__ w2,
    const unsigned short* __restrict__ gtb, const float* __restrict__ bias,
    const float* __restrict__ w3, const int* __restrict__ idx3,
    unsigned short* __restrict__ ybf, float* __restrict__ ps, float* __restrict__ pq)
{
    __shared__ __align__(16) char smem[17408];             // union: Bt | red
    unsigned short (*Bt)[136] = (unsigned short (*)[136])smem;
    float* red = (float*)smem;                             // [256][17]
    __shared__ float wc[64][3];
    __shared__ int   ic[64][3];

    int b = blockIdx.y, n0 = blockIdx.x * 64, t = threadIdx.x;
    int blin = b * gridDim.x + blockIdx.x;

    if (t < 192) {
        int n = t / 3, k = t - n * 3;
        wc[n][k] = w3[((size_t)b * kNL + n0 + n) * 3 + k];
        ic[n][k] = idx3[((size_t)b * kNL + n0 + n) * 3 + k];
    }
    const float* src = flow + (size_t)b * kCL * kNL + n0;
    // 64 c-pairs x 16 n4-groups, 4 units/thread
    #pragma unroll
    for (int i = 0; i < 4; ++i) {
        int e = t + i * 256, cp = e >> 4, n4 = e & 15;
        f32x4 a  = *(const f32x4*)(src + (size_t)(2 * cp)     * kNL + 4 * n4);
        f32x4 b2 = *(const f32x4*)(src + (size_t)(2 * cp + 1) * kNL + 4 * n4);
        #pragma unroll
        for (int r = 0; r < 4; ++r)
            *(unsigned int*)(&Bt[4 * n4 + r][2 * cp]) = f2bf_pk(a[r], b2[r]);
    }
    __syncthreads();

    int w = t >> 6, lane = t & 63, lo = lane & 15, hi = lane >> 4;
    f32x4 vz = {0.f, 0.f, 0.f, 0.f};
    f32x4 acc[4][4];
    #pragma unroll
    for (int mi = 0; mi < 4; ++mi)
        #pragma unroll
        for (int ni = 0; ni < 4; ++ni) acc[mi][ni] = vz;

    #pragma unroll
    for (int ks = 0; ks < 4; ++ks) {
        s16x8 av[4], bv[4];
        #pragma unroll
        for (int mi = 0; mi < 4; ++mi)
            av[mi] = *(const s16x8*)(w2 + (size_t)(64 * w + 16 * mi + lo) * kCL + ks * 32 + hi * 8);
        #pragma unroll
        for (int ni = 0; ni < 4; ++ni)
            bv[ni] = *(const s16x8*)(&Bt[16 * ni + lo][ks * 32 + hi * 8]);
        #pragma unroll
        for (int mi = 0; mi < 4; ++mi)
            #pragma unroll
            for (int ni = 0; ni < 4; ++ni)
                acc[mi][ni] = __builtin_amdgcn_mfma_f32_16x16x32_bf16(av[mi], bv[ni], acc[mi][ni], 0, 0, 0);
    }

    // gather: per neighbor k, stage 8 loads in registers, then convert+FMA
    const unsigned short* Gb = gtb + (size_t)b * kNH * kOUT + w * 64 + hi * 16;
    #pragma unroll
    for (int k = 0; k < 3; ++k) {
        u16x8 g0[4], g1[4];
        float wcr[4];
        #pragma unroll
        for (int ni = 0; ni < 4; ++ni) {
            int lc = 16 * ni + lo;
            int jj = ic[lc][k];
            wcr[ni] = wc[lc][k];
            const u16x8* p = (const u16x8*)(Gb + (size_t)jj * kOUT);
            g0[ni] = p[0];
            g1[ni] = p[1];
        }
        #pragma unroll
        for (int ni = 0; ni < 4; ++ni) {
            float wg = wcr[ni];
            #pragma unroll
            for (int r = 0; r < 4; ++r) {
                acc[0][ni][r] = fmaf(wg, bf2f(g0[ni][r]),     acc[0][ni][r]);
                acc[1][ni][r] = fmaf(wg, bf2f(g0[ni][4 + r]), acc[1][ni][r]);
                acc[2][ni][r] = fmaf(wg, bf2f(g1[ni][r]),     acc[2][ni][r]);
                acc[3][ni][r] = fmaf(wg, bf2f(g1[ni][4 + r]), acc[3][ni][r]);
            }
        }
    }
    #pragma unroll
    for (int mi = 0; mi < 4; ++mi) {
        f32x4 bb = *(const f32x4*)(bias + 64 * w + 16 * mi + 4 * hi);
        #pragma unroll
        for (int ni = 0; ni < 4; ++ni) acc[mi][ni] += bb;
    }

    // store y (bf16)
    unsigned short* Y = ybf + (size_t)b * kOUT * kNL + n0;
    #pragma unroll
    for (int mi = 0; mi < 4; ++mi)
        #pragma unroll
        for (int ni = 0; ni < 4; ++ni)
            #pragma unroll
            for (int r = 0; r < 4; ++r)
                Y[(size_t)(64 * w + 16 * mi + 4 * hi + r) * kNL + 16 * ni + lo] = f2bf(acc[mi][ni][r]);

    // fused partial BN stats (from f32 accs), two rounds through red table
    int ow = t >> 6, omi = (t >> 4) & 3, ohi = (t >> 2) & 3, orr = t & 3;
    __syncthreads();   // Bt dead
    #pragma unroll
    for (int mi = 0; mi < 4; ++mi) {
        f32x4 s = acc[mi][0] + acc[mi][1] + acc[mi][2] + acc[mi][3];
        #pragma unroll
        for (int r = 0; r < 4; ++r) red[t * 17 + mi * 4 + r] = s[r];
    }
    __syncthreads();
    float ssum = 0.0f;
    #pragma unroll
    for (int l2 = 0; l2 < 16; ++l2)
        ssum += red[(ow * 64 + ohi * 16 + l2) * 17 + omi * 4 + orr];
    __syncthreads();
    #pragma unroll
    for (int mi = 0; mi < 4; ++mi) {
        f32x4 q = acc[mi][0] * acc[mi][0] + acc[mi][1] * acc[mi][1]
                + acc[mi][2] * acc[mi][2] + acc[mi][3] * acc[mi][3];
        #pragma unroll
        for (int r = 0; r < 4; ++r) red[t * 17 + mi * 4 + r] = q[r];
    }
    __syncthreads();
    float qsum = 0.0f;
    #pragma unroll
    for (int l2 = 0; l2 < 16; ++l2)
        qsum += red[(ow * 64 + ohi * 16 + l2) * 17 + omi * 4 + orr];

    ps[(size_t)t * 1024 + blin] = ssum;
    pq[(size_t)t * 1024 + blin] = qsum;
}

// ---------------------------------------------------------------------------
__global__ void k_finalize(const float* __restrict__ ps, const float* __restrict__ pq,
                           const float* __restrict__ gamma, const float* __restrict__ beta,
                           float* __restrict__ cA, float* __restrict__ cB) {
    int o = blockIdx.x, t = threadIdx.x;
    float s = 0.0f, q = 0.0f;
    #pragma unroll
    for (int i = 0; i < 4; ++i) {
        s += ps[(size_t)o * 1024 + t + i * 256];
        q += pq[(size_t)o * 1024 + t + i * 256];
    }
    #pragma unroll
    for (int off = 32; off > 0; off >>= 1) {
        s += __shfl_down(s, off);
        q += __shfl_down(q, off);
    }
    __shared__ float ls[4], lq[4];
    if ((t & 63) == 0) { ls[t >> 6] = s; lq[t >> 6] = q; }
    __syncthreads();
    if (t == 0) {
        s = ls[0] + ls[1] + ls[2] + ls[3];
        q = lq[0] + lq[1] + lq[2] + lq[3];
        const float inv = 1.0f / (float)(kB * kNL);
        float mean = s * inv;
        float var  = q * inv - mean * mean;
        float a = gamma[o] * rsqrtf(var + 1e-5f);
        cA[o] = a;
        cB[o] = beta[o] - mean * a;
    }
}

// ---------------------------------------------------------------------------
// apply: read bf16 y (32 MB), write normalized+ReLU f32 out (64 MB)
// ---------------------------------------------------------------------------
__global__ void k_apply(const unsigned short* __restrict__ ybf, float* __restrict__ out,
                        const float* __restrict__ cA, const float* __restrict__ cB) {
    size_t idx    = (size_t)blockIdx.x * 256 + threadIdx.x;
    size_t stride = (size_t)gridDim.x * 256;
    const size_t n8 = (size_t)kB * kOUT * kNL / 8;
    const u16x8* yp = (const u16x8*)ybf;
    float4* op = (float4*)out;
    for (size_t i = idx; i < n8; i += stride) {
        int o = (int)((i >> 9) & 255);   // 512 u16x8 per (b,o) row
        float a = cA[o], c = cB[o];
        u16x8 v = yp[i];
        float4 r0, r1;
        r0.x = fmaxf(fmaf(a, bf2f(v[0]), c), 0.0f);
        r0.y = fmaxf(fmaf(a, bf2f(v[1]), c), 0.0f);
        r0.z = fmaxf(fmaf(a, bf2f(v[2]), c), 0.0f);
        r0.w = fmaxf(fmaf(a, bf2f(v[3]), c), 0.0f);
        r1.x = fmaxf(fmaf(a, bf2f(v[4]), c), 0.0f);
        r1.y = fmaxf(fmaf(a, bf2f(v[5]), c), 0.0f);
        r1.z = fmaxf(fmaf(a, bf2f(v[6]), c), 0.0f);
        r1.w = fmaxf(fmaf(a, bf2f(v[7]), c), 0.0f);
        op[2 * i]     = r0;
        op[2 * i + 1] = r1;
    }
}

// ---------------------------------------------------------------------------
extern "C" void kernel_launch(void* const* d_in, const int* in_sizes, int n_in,
                              void* d_out, int out_size, void* d_ws, size_t ws_size,
                              hipStream_t stream) {
    const float* xyzl  = (const float*)d_in[0];
    const float* xyzh  = (const float*)d_in[1];
    const float* flow  = (const float*)d_in[2];
    const float* fhigh = (const float*)d_in[3];
    const float* W     = (const float*)d_in[4];
    const float* bias  = (const float*)d_in[5];
    const float* gamma = (const float*)d_in[6];
    const float* beta  = (const float*)d_in[7];
    float* out = (float*)d_out;
    char*  ws  = (char*)d_ws;
    (void)in_sizes; (void)n_in; (void)out_size; (void)ws_size;

    // ws layout (bytes), total ~44 MB
    float*          w3   = (float*)(ws + 0);                   // 786432
    int*            idx3 = (int*)  (ws + 786432);              // 786432
    unsigned short* gtb  = (unsigned short*)(ws + 1572864);    // 8 MB (bf16, permuted)
    unsigned short* ybf  = (unsigned short*)(ws + 9961472);    // 32 MB (bf16 y)
    unsigned short* w1   = (unsigned short*)(ws + 43515904);   // 128 KB
    unsigned short* w2   = (unsigned short*)(ws + 43646976);   // 64 KB
    float*          ps   = (float*)(ws + 43712512);            // 1 MB
    float*          pq   = (float*)(ws + 44761088);            // 1 MB
    float*          cA   = (float*)(ws + 45809664);            // 1 KB
    float*          cB   = (float*)(ws + 45810688);            // 1 KB
    float4*         cand = (float4*)(ws + 45811712);           // 256 KB

    hipLaunchKernelGGL(k_prep_w,    dim3(256),          dim3(384), 0, stream, W, w1, w2);
    hipLaunchKernelGGL(k_prep_cand, dim3(kB),           dim3(256), 0, stream, xyzh, cand);
    hipLaunchKernelGGL(k_three_nn,  dim3(kNL / 64, kB), dim3(512), 0, stream, xyzl, cand, w3, idx3);
    hipLaunchKernelGGL(k_gemm1,     dim3(kNH / 64, kB), dim3(256), 0, stream, fhigh, w1, gtb);
    hipLaunchKernelGGL(k_gemm2,     dim3(kNL / 64, kB), dim3(256), 0, stream,
                       flow, w2, gtb, bias, w3, idx3, ybf, ps, pq);
    hipLaunchKernelGGL(k_finalize,  dim3(256),          dim3(256), 0, stream, ps, pq, gamma, beta, cA, cB);
    hipLaunchKernelGGL(k_apply,     dim3(2048),         dim3(256), 0, stream, ybf, out, cA, cB);
}

// Round 6
// 104.165 us; speedup vs baseline: 3.9405x; 1.1699x over previous
//
#include <hip/hip_runtime.h>
#include <math.h>

constexpr int kB   = 16;
constexpr int kNL  = 4096;
constexpr int kNH  = 1024;
constexpr int kCL  = 128;
constexpr int kCH  = 256;
constexpr int kOUT = 256;

typedef __attribute__((ext_vector_type(8))) short s16x8;
typedef __attribute__((ext_vector_type(8))) unsigned short u16x8;
typedef __attribute__((ext_vector_type(4))) unsigned short u16x4;
typedef __attribute__((ext_vector_type(4))) float f32x4;

__device__ __forceinline__ unsigned short f2bf(float x) {
    unsigned int u = __float_as_uint(x);
    return (unsigned short)((u + 0x7FFFu + ((u >> 16) & 1u)) >> 16);
}
__device__ __forceinline__ unsigned int f2bf_pk(float a, float b) {
    return (unsigned int)f2bf(a) | ((unsigned int)f2bf(b) << 16);
}
__device__ __forceinline__ float bf2f(unsigned short h) {
    return __uint_as_float((unsigned int)h << 16);
}

// ---------------------------------------------------------------------------
// W (256x384 f32) -> W1bf (256x256 bf16), W2bf (256x128 bf16)
// ---------------------------------------------------------------------------
__global__ void k_prep_w(const float* __restrict__ W, unsigned short* __restrict__ w1,
                         unsigned short* __restrict__ w2) {
    int o = blockIdx.x, k = threadIdx.x;
    float v = W[o * 384 + k];
    if (k < kCH) w1[o * kCH + k] = f2bf(v);
    else         w2[o * kCL + (k - kCH)] = f2bf(v);
}

// ---------------------------------------------------------------------------
// cand[b][j] = {2x, 2y, 2z, x^2+y^2+z^2}; pre-doubling is fp-exact.
// ---------------------------------------------------------------------------
__global__ void k_prep_cand(const float* __restrict__ xyzh, float4* __restrict__ cand) {
    int b = blockIdx.x;
    const float* H = xyzh + (size_t)b * kNH * 3;
    for (int j = threadIdx.x; j < kNH; j += 256) {
        float xx = H[j * 3 + 0], yy = H[j * 3 + 1], zz = H[j * 3 + 2];
        float s = __fmul_rn(xx, xx);
        s = __fadd_rn(s, __fmul_rn(yy, yy));
        s = __fadd_rn(s, __fmul_rn(zz, zz));
        cand[(size_t)b * kNH + j] = make_float4(xx + xx, yy + yy, zz + zz, s);
    }
}

// ---------------------------------------------------------------------------
// GEMM1: G = W1 x feat_high per batch. Reads fhigh f32 directly, converts
// to bf16 while staging into LDS. Output gtb bf16 in fragment-permuted
// layout [w][hi][mi][r] (channel o = 64w+16mi+4hi+r).
// ---------------------------------------------------------------------------
__global__ __launch_bounds__(256, 4) void k_gemm1(
    const float* __restrict__ fhigh, const unsigned short* __restrict__ w1,
    unsigned short* __restrict__ gtb)
{
    __shared__ __align__(16) unsigned short Bt[64][264];
    int b = blockIdx.y, j0 = blockIdx.x * 64, t = threadIdx.x;
    const float* src = fhigh + (size_t)b * kCH * kNH + j0;
    #pragma unroll
    for (int i = 0; i < 8; ++i) {
        int e = t + i * 256, cp = e >> 4, j4 = e & 15;
        f32x4 a  = *(const f32x4*)(src + (size_t)(2 * cp)     * kNH + 4 * j4);
        f32x4 b2 = *(const f32x4*)(src + (size_t)(2 * cp + 1) * kNH + 4 * j4);
        #pragma unroll
        for (int r = 0; r < 4; ++r)
            *(unsigned int*)(&Bt[4 * j4 + r][2 * cp]) = f2bf_pk(a[r], b2[r]);
    }
    __syncthreads();

    int w = t >> 6, lane = t & 63, lo = lane & 15, hi = lane >> 4;
    f32x4 vz = {0.f, 0.f, 0.f, 0.f};
    f32x4 acc[4][4];
    #pragma unroll
    for (int mi = 0; mi < 4; ++mi)
        #pragma unroll
        for (int ni = 0; ni < 4; ++ni) acc[mi][ni] = vz;

    #pragma unroll
    for (int ks = 0; ks < 8; ++ks) {
        s16x8 av[4], bv[4];
        #pragma unroll
        for (int mi = 0; mi < 4; ++mi)
            av[mi] = *(const s16x8*)(w1 + (size_t)(64 * w + 16 * mi + lo) * kCH + ks * 32 + hi * 8);
        #pragma unroll
        for (int ni = 0; ni < 4; ++ni)
            bv[ni] = *(const s16x8*)(&Bt[16 * ni + lo][ks * 32 + hi * 8]);
        #pragma unroll
        for (int mi = 0; mi < 4; ++mi)
            #pragma unroll
            for (int ni = 0; ni < 4; ++ni)
                acc[mi][ni] = __builtin_amdgcn_mfma_f32_16x16x32_bf16(av[mi], bv[ni], acc[mi][ni], 0, 0, 0);
    }

    unsigned short* G = gtb + ((size_t)b * kNH + j0) * kOUT;
    #pragma unroll
    for (int mi = 0; mi < 4; ++mi)
        #pragma unroll
        for (int ni = 0; ni < 4; ++ni) {
            f32x4 a = acc[mi][ni];
            u16x4 h;
            #pragma unroll
            for (int r = 0; r < 4; ++r) h[r] = f2bf(a[r]);
            *(u16x4*)(&G[(size_t)(16 * ni + lo) * kOUT + w * 64 + hi * 16 + mi * 4]) = h;
        }
}

// ---------------------------------------------------------------------------
// FUSED: three_nn + GEMM2 + interp-gather + bias + partial BN stats.
// The 64-point neighbor search runs inside the block (VALU) and overlaps,
// across co-resident blocks, with the staging/gather/store memory phases.
// Even/odd blocks swap the {K-loop, nn-scan} order to stagger pipe usage.
// ---------------------------------------------------------------------------
__global__ __launch_bounds__(256, 4) void k_gemm2(
    const float* __restrict__ flow, const unsigned short* __restrict__ w2,
    const unsigned short* __restrict__ gtb, const float* __restrict__ bias,
    const float* __restrict__ xyzl, const float4* __restrict__ cand,
    unsigned short* __restrict__ ybf, float* __restrict__ ps, float* __restrict__ pq)
{
    __shared__ __align__(16) char smem[17408];             // union: Bt | red
    unsigned short (*Bt)[136] = (unsigned short (*)[136])smem;
    float* red = (float*)smem;                             // [256][17]
    __shared__ float wc[64][3];
    __shared__ int   ic[64][3];
    __shared__ float md[64][4][3];
    __shared__ int   midx[64][4][3];

    int b = blockIdx.y, n0 = blockIdx.x * 64, t = threadIdx.x;
    int blin = b * gridDim.x + blockIdx.x;

    // --- stage feat_low tile (f32 -> packed bf16) into Bt ---
    const float* src = flow + (size_t)b * kCL * kNL + n0;
    #pragma unroll
    for (int i = 0; i < 4; ++i) {
        int e = t + i * 256, cp = e >> 4, n4 = e & 15;
        f32x4 a  = *(const f32x4*)(src + (size_t)(2 * cp)     * kNL + 4 * n4);
        f32x4 b2 = *(const f32x4*)(src + (size_t)(2 * cp + 1) * kNL + 4 * n4);
        #pragma unroll
        for (int r = 0; r < 4; ++r)
            *(unsigned int*)(&Bt[4 * n4 + r][2 * cp]) = f2bf_pk(a[r], b2[r]);
    }
    __syncthreads();

    int w = t >> 6, lane = t & 63, lo = lane & 15, hi = lane >> 4;
    f32x4 vz = {0.f, 0.f, 0.f, 0.f};
    f32x4 acc[4][4];
    #pragma unroll
    for (int mi = 0; mi < 4; ++mi)
        #pragma unroll
        for (int ni = 0; ni < 4; ++ni) acc[mi][ni] = vz;

    // --- nn-scan: this block's 64 points, 4 j-subranges x (2 ILP streams) ---
    auto do_nn = [&]() {
        int sub = t >> 6, ll = t & 63;
        int l = n0 + ll;
        const float* L = xyzl + ((size_t)b * kNL + l) * 3;
        float x = L[0], y = L[1], z = L[2];
        float sql = __fmul_rn(x, x);
        sql = __fadd_rn(sql, __fmul_rn(y, y));
        sql = __fadd_rn(sql, __fmul_rn(z, z));

        float dA0 = 1e30f, dA1 = 1e30f, dA2 = 1e30f;
        int   iA0 = 0,     iA1 = 0,     iA2 = 0;
        float dB0 = 1e30f, dB1 = 1e30f, dB2 = 1e30f;
        int   iB0 = 0,     iB1 = 0,     iB2 = 0;

        int jbeg = __builtin_amdgcn_readfirstlane(sub << 8);   // 256 cands/sub
        const float4* C = cand + ((size_t)b << 10) + jbeg;

        #pragma unroll 4
        for (int jj = 0; jj < 128; ++jj) {
            {   // stream A: [jbeg, jbeg+128)
                float4 c = C[jj];
                float inner2 = __fmul_rn(x, c.x);
                inner2 = __fadd_rn(inner2, __fmul_rn(y, c.y));
                inner2 = __fadd_rn(inner2, __fmul_rn(z, c.z));
                float dsq = __fsub_rn(__fadd_rn(sql, c.w), inner2);
                dsq = fmaxf(dsq, 0.0f);
                int j = jbeg + jj;
                bool c0 = dsq < dA0, c1 = dsq < dA1, c2 = dsq < dA2;
                float td = c1 ? dA1 : dsq;  int ti = c1 ? iA1 : j;
                dA2 = c2 ? td : dA2;        iA2 = c2 ? ti : iA2;
                td = c0 ? dA0 : dsq;        ti = c0 ? iA0 : j;
                dA1 = c1 ? td : dA1;        iA1 = c1 ? ti : iA1;
                dA0 = c0 ? dsq : dA0;       iA0 = c0 ? j : iA0;
            }
            {   // stream B: [jbeg+128, jbeg+256)
                float4 c = C[128 + jj];
                float inner2 = __fmul_rn(x, c.x);
                inner2 = __fadd_rn(inner2, __fmul_rn(y, c.y));
                inner2 = __fadd_rn(inner2, __fmul_rn(z, c.z));
                float dsq = __fsub_rn(__fadd_rn(sql, c.w), inner2);
                dsq = fmaxf(dsq, 0.0f);
                int j = jbeg + 128 + jj;
                bool c0 = dsq < dB0, c1 = dsq < dB1, c2 = dsq < dB2;
                float td = c1 ? dB1 : dsq;  int ti = c1 ? iB1 : j;
                dB2 = c2 ? td : dB2;        iB2 = c2 ? ti : iB2;
                td = c0 ? dB0 : dsq;        ti = c0 ? iB0 : j;
                dB1 = c1 ? td : dB1;        iB1 = c1 ? ti : iB1;
                dB0 = c0 ? dsq : dB0;       iB0 = c0 ? j : iB0;
            }
        }

        // merge stream B into A, lex (d, idx) = top_k tie semantics
        #pragma unroll
        for (int m = 0; m < 3; ++m) {
            float d = (m == 0) ? dB0 : (m == 1) ? dB1 : dB2;
            int  ii = (m == 0) ? iB0 : (m == 1) ? iB1 : iB2;
            bool lt2 = (d < dA2) || (d == dA2 && ii < iA2);
            if (lt2) {
                bool lt0 = (d < dA0) || (d == dA0 && ii < iA0);
                bool lt1 = (d < dA1) || (d == dA1 && ii < iA1);
                if (lt0)      { dA2 = dA1; iA2 = iA1; dA1 = dA0; iA1 = iA0; dA0 = d; iA0 = ii; }
                else if (lt1) { dA2 = dA1; iA2 = iA1; dA1 = d; iA1 = ii; }
                else          { dA2 = d; iA2 = ii; }
            }
        }

        md[ll][sub][0] = dA0;  md[ll][sub][1] = dA1;  md[ll][sub][2] = dA2;
        midx[ll][sub][0] = iA0; midx[ll][sub][1] = iA1; midx[ll][sub][2] = iA2;
        __syncthreads();

        if (sub == 0) {
            float e0 = 1e30f, e1 = 1e30f, e2 = 1e30f;
            int   a0 = 0x7fffffff, a1 = 0x7fffffff, a2 = 0x7fffffff;
            #pragma unroll
            for (int s = 0; s < 4; ++s) {
                #pragma unroll
                for (int k = 0; k < 3; ++k) {
                    float d = md[ll][s][k]; int ii = midx[ll][s][k];
                    bool lt2 = (d < e2) || (d == e2 && ii < a2);
                    if (lt2) {
                        bool lt0 = (d < e0) || (d == e0 && ii < a0);
                        bool lt1 = (d < e1) || (d == e1 && ii < a1);
                        if (lt0)      { e2 = e1; a2 = a1; e1 = e0; a1 = a0; e0 = d; a0 = ii; }
                        else if (lt1) { e2 = e1; a2 = a1; e1 = d; a1 = ii; }
                        else          { e2 = d; a2 = ii; }
                    }
                }
            }
            float q0 = fmaxf(sqrtf(e0), 1e-8f);
            float q1 = fmaxf(sqrtf(e1), 1e-8f);
            float q2 = fmaxf(sqrtf(e2), 1e-8f);
            float r0 = 1.0f / q0, r1 = 1.0f / q1, r2 = 1.0f / q2;
            float s = __fadd_rn(__fadd_rn(r0, r1), r2);
            wc[ll][0] = r0 / s;  wc[ll][1] = r1 / s;  wc[ll][2] = r2 / s;
            ic[ll][0] = a0;      ic[ll][1] = a1;      ic[ll][2] = a2;
        }
    };

    // --- MFMA K-loop: y += W2 x feat_low_tile ---
    auto do_kloop = [&]() {
        #pragma unroll
        for (int ks = 0; ks < 4; ++ks) {
            s16x8 av[4], bv[4];
            #pragma unroll
            for (int mi = 0; mi < 4; ++mi)
                av[mi] = *(const s16x8*)(w2 + (size_t)(64 * w + 16 * mi + lo) * kCL + ks * 32 + hi * 8);
            #pragma unroll
            for (int ni = 0; ni < 4; ++ni)
                bv[ni] = *(const s16x8*)(&Bt[16 * ni + lo][ks * 32 + hi * 8]);
            #pragma unroll
            for (int mi = 0; mi < 4; ++mi)
                #pragma unroll
                for (int ni = 0; ni < 4; ++ni)
                    acc[mi][ni] = __builtin_amdgcn_mfma_f32_16x16x32_bf16(av[mi], bv[ni], acc[mi][ni], 0, 0, 0);
        }
    };

    // phase stagger across co-resident blocks
    if (blockIdx.x & 1) { do_kloop(); do_nn(); }
    else                { do_nn();    do_kloop(); }
    __syncthreads();   // wc/ic visible; everyone done with Bt

    // --- gather: per neighbor k, stage 8 loads in registers, then FMA ---
    const unsigned short* Gb = gtb + (size_t)b * kNH * kOUT + w * 64 + hi * 16;
    #pragma unroll
    for (int k = 0; k < 3; ++k) {
        u16x8 g0[4], g1[4];
        float wcr[4];
        #pragma unroll
        for (int ni = 0; ni < 4; ++ni) {
            int lc = 16 * ni + lo;
            int jj = ic[lc][k];
            wcr[ni] = wc[lc][k];
            const u16x8* p = (const u16x8*)(Gb + (size_t)jj * kOUT);
            g0[ni] = p[0];
            g1[ni] = p[1];
        }
        #pragma unroll
        for (int ni = 0; ni < 4; ++ni) {
            float wg = wcr[ni];
            #pragma unroll
            for (int r = 0; r < 4; ++r) {
                acc[0][ni][r] = fmaf(wg, bf2f(g0[ni][r]),     acc[0][ni][r]);
                acc[1][ni][r] = fmaf(wg, bf2f(g0[ni][4 + r]), acc[1][ni][r]);
                acc[2][ni][r] = fmaf(wg, bf2f(g1[ni][r]),     acc[2][ni][r]);
                acc[3][ni][r] = fmaf(wg, bf2f(g1[ni][4 + r]), acc[3][ni][r]);
            }
        }
    }
    #pragma unroll
    for (int mi = 0; mi < 4; ++mi) {
        f32x4 bb = *(const f32x4*)(bias + 64 * w + 16 * mi + 4 * hi);
        #pragma unroll
        for (int ni = 0; ni < 4; ++ni) acc[mi][ni] += bb;
    }

    // store y (bf16)
    unsigned short* Y = ybf + (size_t)b * kOUT * kNL + n0;
    #pragma unroll
    for (int mi = 0; mi < 4; ++mi)
        #pragma unroll
        for (int ni = 0; ni < 4; ++ni)
            #pragma unroll
            for (int r = 0; r < 4; ++r)
                Y[(size_t)(64 * w + 16 * mi + 4 * hi + r) * kNL + 16 * ni + lo] = f2bf(acc[mi][ni][r]);

    // fused partial BN stats (from f32 accs), two rounds through red table
    int ow = t >> 6, omi = (t >> 4) & 3, ohi = (t >> 2) & 3, orr = t & 3;
    __syncthreads();   // Bt dead -> red
    #pragma unroll
    for (int mi = 0; mi < 4; ++mi) {
        f32x4 s = acc[mi][0] + acc[mi][1] + acc[mi][2] + acc[mi][3];
        #pragma unroll
        for (int r = 0; r < 4; ++r) red[t * 17 + mi * 4 + r] = s[r];
    }
    __syncthreads();
    float ssum = 0.0f;
    #pragma unroll
    for (int l2 = 0; l2 < 16; ++l2)
        ssum += red[(ow * 64 + ohi * 16 + l2) * 17 + omi * 4 + orr];
    __syncthreads();
    #pragma unroll
    for (int mi = 0; mi < 4; ++mi) {
        f32x4 q = acc[mi][0] * acc[mi][0] + acc[mi][1] * acc[mi][1]
                + acc[mi][2] * acc[mi][2] + acc[mi][3] * acc[mi][3];
        #pragma unroll
        for (int r = 0; r < 4; ++r) red[t * 17 + mi * 4 + r] = q[r];
    }
    __syncthreads();
    float qsum = 0.0f;
    #pragma unroll
    for (int l2 = 0; l2 < 16; ++l2)
        qsum += red[(ow * 64 + ohi * 16 + l2) * 17 + omi * 4 + orr];

    ps[(size_t)t * 1024 + blin] = ssum;
    pq[(size_t)t * 1024 + blin] = qsum;
}

// ---------------------------------------------------------------------------
__global__ void k_finalize(const float* __restrict__ ps, const float* __restrict__ pq,
                           const float* __restrict__ gamma, const float* __restrict__ beta,
                           float* __restrict__ cA, float* __restrict__ cB) {
    int o = blockIdx.x, t = threadIdx.x;
    float s = 0.0f, q = 0.0f;
    #pragma unroll
    for (int i = 0; i < 4; ++i) {
        s += ps[(size_t)o * 1024 + t + i * 256];
        q += pq[(size_t)o * 1024 + t + i * 256];
    }
    #pragma unroll
    for (int off = 32; off > 0; off >>= 1) {
        s += __shfl_down(s, off);
        q += __shfl_down(q, off);
    }
    __shared__ float ls[4], lq[4];
    if ((t & 63) == 0) { ls[t >> 6] = s; lq[t >> 6] = q; }
    __syncthreads();
    if (t == 0) {
        s = ls[0] + ls[1] + ls[2] + ls[3];
        q = lq[0] + lq[1] + lq[2] + lq[3];
        const float inv = 1.0f / (float)(kB * kNL);
        float mean = s * inv;
        float var  = q * inv - mean * mean;
        float a = gamma[o] * rsqrtf(var + 1e-5f);
        cA[o] = a;
        cB[o] = beta[o] - mean * a;
    }
}

// ---------------------------------------------------------------------------
// apply: read bf16 y (32 MB), write normalized+ReLU f32 out (64 MB)
// ---------------------------------------------------------------------------
__global__ void k_apply(const unsigned short* __restrict__ ybf, float* __restrict__ out,
                        const float* __restrict__ cA, const float* __restrict__ cB) {
    size_t idx    = (size_t)blockIdx.x * 256 + threadIdx.x;
    size_t stride = (size_t)gridDim.x * 256;
    const size_t n8 = (size_t)kB * kOUT * kNL / 8;
    const u16x8* yp = (const u16x8*)ybf;
    float4* op = (float4*)out;
    for (size_t i = idx; i < n8; i += stride) {
        int o = (int)((i >> 9) & 255);   // 512 u16x8 per (b,o) row
        float a = cA[o], c = cB[o];
        u16x8 v = yp[i];
        float4 r0, r1;
        r0.x = fmaxf(fmaf(a, bf2f(v[0]), c), 0.0f);
        r0.y = fmaxf(fmaf(a, bf2f(v[1]), c), 0.0f);
        r0.z = fmaxf(fmaf(a, bf2f(v[2]), c), 0.0f);
        r0.w = fmaxf(fmaf(a, bf2f(v[3]), c), 0.0f);
        r1.x = fmaxf(fmaf(a, bf2f(v[4]), c), 0.0f);
        r1.y = fmaxf(fmaf(a, bf2f(v[5]), c), 0.0f);
        r1.z = fmaxf(fmaf(a, bf2f(v[6]), c), 0.0f);
        r1.w = fmaxf(fmaf(a, bf2f(v[7]), c), 0.0f);
        op[2 * i]     = r0;
        op[2 * i + 1] = r1;
    }
}

// ---------------------------------------------------------------------------
extern "C" void kernel_launch(void* const* d_in, const int* in_sizes, int n_in,
                              void* d_out, int out_size, void* d_ws, size_t ws_size,
                              hipStream_t stream) {
    const float* xyzl  = (const float*)d_in[0];
    const float* xyzh  = (const float*)d_in[1];
    const float* flow  = (const float*)d_in[2];
    const float* fhigh = (const float*)d_in[3];
    const float* W     = (const float*)d_in[4];
    const float* bias  = (const float*)d_in[5];
    const float* gamma = (const float*)d_in[6];
    const float* beta  = (const float*)d_in[7];
    float* out = (float*)d_out;
    char*  ws  = (char*)d_ws;
    (void)in_sizes; (void)n_in; (void)out_size; (void)ws_size;

    // ws layout (bytes), total ~44.5 MB
    unsigned short* gtb  = (unsigned short*)(ws + 0);          // 8 MB (bf16, permuted)
    unsigned short* ybf  = (unsigned short*)(ws + 8388608);    // 32 MB (bf16 y)
    unsigned short* w1   = (unsigned short*)(ws + 41943040);   // 128 KB
    unsigned short* w2   = (unsigned short*)(ws + 42074112);   // 64 KB
    float*          ps   = (float*)(ws + 42139648);            // 1 MB
    float*          pq   = (float*)(ws + 43188224);            // 1 MB
    float*          cA   = (float*)(ws + 44236800);            // 1 KB
    float*          cB   = (float*)(ws + 44237824);            // 1 KB
    float4*         cand = (float4*)(ws + 44238848);           // 256 KB

    hipLaunchKernelGGL(k_prep_w,    dim3(256),          dim3(384), 0, stream, W, w1, w2);
    hipLaunchKernelGGL(k_prep_cand, dim3(kB),           dim3(256), 0, stream, xyzh, cand);
    hipLaunchKernelGGL(k_gemm1,     dim3(kNH / 64, kB), dim3(256), 0, stream, fhigh, w1, gtb);
    hipLaunchKernelGGL(k_gemm2,     dim3(kNL / 64, kB), dim3(256), 0, stream,
                       flow, w2, gtb, bias, xyzl, cand, ybf, ps, pq);
    hipLaunchKernelGGL(k_finalize,  dim3(256),          dim3(256), 0, stream, ps, pq, gamma, beta, cA, cB);
    hipLaunchKernelGGL(k_apply,     dim3(2048),         dim3(256), 0, stream, ybf, out, cA, cB);
}